// Round 15
// baseline (1791.028 us; speedup 1.0000x reference)
//
#include <hip/hip_runtime.h>
#include <math.h>

#define TT 1024
#define DD 1024
#define NH 16
#define NB 2
#define NL 12
#define RR 32
#define MM (NB * TT)  // 2048

typedef __attribute__((ext_vector_type(8))) short bf16x8;
typedef __attribute__((ext_vector_type(4))) float f32x4;

__device__ __forceinline__ unsigned short f2bf(float f) {
  unsigned int u = __float_as_uint(f);
  u = (u + 0x7FFFu + ((u >> 16) & 1u)) >> 16;
  return (unsigned short)u;
}
__device__ __forceinline__ float bf2f(unsigned short u) {
  return __uint_as_float((unsigned int)u << 16);
}

typedef __attribute__((address_space(1))) void gvoid;
typedef __attribute__((address_space(3))) void lvoid;
__device__ __forceinline__ void gload_lds16(const void* g, void* l) {
  __builtin_amdgcn_global_load_lds((gvoid*)g, (lvoid*)l, 16, 0, 0);
}

// ---------------------------------------------------------------- embed + LoRA cvt (merged, independent)
__global__ __launch_bounds__(256) void embed_cvt_k(
    const int* __restrict__ ids, const float* __restrict__ wte,
    const float* __restrict__ wpe, float* __restrict__ h,
    const float* __restrict__ ala, const float* __restrict__ alb,
    const float* __restrict__ pla, const float* __restrict__ plb,
    const float* __restrict__ fla, const float* __restrict__ flb,
    const float* __restrict__ mla, const float* __restrict__ mlb,
    unsigned short* __restrict__ out) {
  if (blockIdx.x < MM * DD / 256) {
    const int i = blockIdx.x * 256 + threadIdx.x;
    const int row = i >> 10;
    const int d = i & 1023;
    const int t = row & (TT - 1);
    const int id = ids[row];
    h[i] = wte[(size_t)id * DD + d] + wpe[(size_t)t * DD + d];
    return;
  }
  const int g = (blockIdx.x - MM * DD / 256) * 256 + threadIdx.x;  // over NL*16384*32
  const int layer = g >> 19;
  const int rem = g & 524287;
  const int row = rem >> 5;
  const int r = rem & 31;
  float v;
  if (row < 1024)       v = ala[(size_t)layer * 32 * 1024 + r * 1024 + row];
  else if (row < 4096)  v = alb[(size_t)layer * 3072 * 32 + (row - 1024) * 32 + r];
  else if (row < 5120)  v = pla[(size_t)layer * 32 * 1024 + r * 1024 + (row - 4096)];
  else if (row < 6144)  v = plb[(size_t)layer * 1024 * 32 + (row - 5120) * 32 + r];
  else if (row < 7168)  v = fla[(size_t)layer * 32 * 1024 + r * 1024 + (row - 6144)];
  else if (row < 11264) v = flb[(size_t)layer * 4096 * 32 + (row - 7168) * 32 + r];
  else if (row < 15360) v = mla[(size_t)layer * 32 * 4096 + r * 4096 + (row - 11264)];
  else                  v = mlb[(size_t)layer * 1024 * 32 + (row - 15360) * 32 + r];
  out[g] = f2bf(v);
}

// ---------------------------------------------------------------- layernorm (fp32 in, bf16 out)
__global__ __launch_bounds__(256) void ln_bf_k(const float* __restrict__ x,
                                               const float* __restrict__ w,
                                               const float* __restrict__ b,
                                               unsigned short* __restrict__ out) {
  const int row = blockIdx.x;
  const float* xr = x + (size_t)row * DD;
  const float4 v = *(const float4*)(xr + threadIdx.x * 4);
  float s = v.x + v.y + v.z + v.w;
  float ss = v.x * v.x + v.y * v.y + v.z * v.z + v.w * v.w;
#pragma unroll
  for (int off = 32; off > 0; off >>= 1) {
    s += __shfl_down(s, off);
    ss += __shfl_down(ss, off);
  }
  __shared__ float rs[4], rss[4];
  const int wid = threadIdx.x >> 6;
  if ((threadIdx.x & 63) == 0) { rs[wid] = s; rss[wid] = ss; }
  __syncthreads();
  s = rs[0] + rs[1] + rs[2] + rs[3];
  ss = rss[0] + rss[1] + rss[2] + rss[3];
  const float mean = s * (1.f / DD);
  const float var = ss * (1.f / DD) - mean * mean;
  const float rstd = rsqrtf(var + 1e-5f);
  const float4 wv = *(const float4*)(w + threadIdx.x * 4);
  const float4 bv = *(const float4*)(b + threadIdx.x * 4);
  ushort4 o;
  o.x = f2bf((v.x - mean) * rstd * wv.x + bv.x);
  o.y = f2bf((v.y - mean) * rstd * wv.y + bv.y);
  o.z = f2bf((v.z - mean) * rstd * wv.z + bv.z);
  o.w = f2bf((v.w - mean) * rstd * wv.w + bv.w);
  *(ushort4*)(out + (size_t)row * DD + threadIdx.x * 4) = o;
}

// final layernorm fp32 out
__global__ __launch_bounds__(256) void ln_f_k(const float* __restrict__ x,
                                              const float* __restrict__ w,
                                              const float* __restrict__ b,
                                              float* __restrict__ out) {
  const int row = blockIdx.x;
  const float* xr = x + (size_t)row * DD;
  const float4 v = *(const float4*)(xr + threadIdx.x * 4);
  float s = v.x + v.y + v.z + v.w;
  float ss = v.x * v.x + v.y * v.y + v.z * v.z + v.w * v.w;
#pragma unroll
  for (int off = 32; off > 0; off >>= 1) {
    s += __shfl_down(s, off);
    ss += __shfl_down(ss, off);
  }
  __shared__ float rs[4], rss[4];
  const int wid = threadIdx.x >> 6;
  if ((threadIdx.x & 63) == 0) { rs[wid] = s; rss[wid] = ss; }
  __syncthreads();
  s = rs[0] + rs[1] + rs[2] + rs[3];
  ss = rss[0] + rss[1] + rss[2] + rss[3];
  const float mean = s * (1.f / DD);
  const float var = ss * (1.f / DD) - mean * mean;
  const float rstd = rsqrtf(var + 1e-5f);
  const float4 wv = *(const float4*)(w + threadIdx.x * 4);
  const float4 bv = *(const float4*)(b + threadIdx.x * 4);
  float4 o;
  o.x = (v.x - mean) * rstd * wv.x + bv.x;
  o.y = (v.y - mean) * rstd * wv.y + bv.y;
  o.z = (v.z - mean) * rstd * wv.z + bv.z;
  o.w = (v.w - mean) * rstd * wv.w + bv.w;
  *(float4*)(out + (size_t)row * DD + threadIdx.x * 4) = o;
}

// ---------------------------------------------------------------- fold device body (shared by two kernels)
__device__ __forceinline__ void fold_body(
    int lid, char* smem,
    const float* __restrict__ aw, const float* __restrict__ pw,
    const float* __restrict__ fw, const float* __restrict__ mw,
    const unsigned short* __restrict__ Lb,
    unsigned short* __restrict__ oq, unsigned short* __restrict__ op_,
    unsigned short* __restrict__ of, unsigned short* __restrict__ om) {
  const float* W;
  unsigned short* out;
  const unsigned short *Bl, *Al;
  int K, n0, kblk;
  if (lid < 384) {
    W = aw; out = oq; Bl = Lb + 1024 * 32; Al = Lb;
    K = DD; n0 = (lid >> 3) * 64; kblk = (lid & 7) * 128;
  } else if (lid < 512) {
    const int t = lid - 384;
    W = pw; out = op_; Bl = Lb + 5120 * 32; Al = Lb + 4096 * 32;
    K = DD; n0 = (t >> 3) * 64; kblk = (t & 7) * 128;
  } else if (lid < 1024) {
    const int t = lid - 512;
    W = fw; out = of; Bl = Lb + 7168 * 32; Al = Lb + 6144 * 32;
    K = DD; n0 = (t >> 3) * 64; kblk = (t & 7) * 128;
  } else {
    const int t = lid - 1024;
    W = mw; out = om; Bl = Lb + 15360 * 32; Al = Lb + 11264 * 32;
    K = 4 * DD; n0 = (t >> 5) * 64; kblk = (t & 31) * 128;
  }
  unsigned short* dl = (unsigned short*)smem;  // 16KB
  const int tid = threadIdx.x;
  const int w = tid >> 6, l = tid & 63;
  const int lr16 = l & 15, lg = l >> 4;
  const int nloc = w * 16 + lr16;
  const bf16x8 bfrag = *(const bf16x8*)(Bl + (size_t)(n0 + nloc) * 32 + lg * 8);
#pragma unroll
  for (int kc = 0; kc < 8; ++kc) {
    const bf16x8 afr = *(const bf16x8*)(Al + (size_t)(kblk + kc * 16 + lr16) * 32 + lg * 8);
    f32x4 acc = {};
    acc = __builtin_amdgcn_mfma_f32_16x16x32_bf16(afr, bfrag, acc, 0, 0, 0);
    ushort4 dv;
    dv.x = f2bf(2.f * acc[0]); dv.y = f2bf(2.f * acc[1]);
    dv.z = f2bf(2.f * acc[2]); dv.w = f2bf(2.f * acc[3]);
    const unsigned int byte = ((unsigned)(nloc * 256 + kc * 32 + lg * 8)) ^
                              (((unsigned)nloc & 3u) << 5);
    *(ushort4*)((char*)dl + byte) = dv;
  }
  __syncthreads();
  float4 wv[8];
#pragma unroll
  for (int it = 0; it < 8; ++it) {
    const int flat = it * 1024 + tid * 4;
    const int row = flat >> 7;
    const int k = flat & 127;
    wv[it] = *(const float4*)(W + (size_t)(n0 + row) * K + kblk + k);
  }
  asm volatile("s_waitcnt vmcnt(0)" ::: "memory");
#pragma unroll
  for (int it = 0; it < 8; ++it) {
    const int flat = it * 1024 + tid * 4;
    const int row = flat >> 7;
    const int k = flat & 127;
    const unsigned int byte = ((unsigned)(row * 256 + k * 2)) ^
                              (((unsigned)row & 3u) << 5);
    const ushort4 dv = *(const ushort4*)((const char*)dl + byte);
    ushort4 o;
    o.x = f2bf(wv[it].x + bf2f(dv.x));
    o.y = f2bf(wv[it].y + bf2f(dv.y));
    o.z = f2bf(wv[it].z + bf2f(dv.z));
    o.w = f2bf(wv[it].w + bf2f(dv.w));
    *(ushort4*)(out + (size_t)(n0 + row) * K + kblk + k) = o;
  }
}

// ---------------------------------------------------------------- merged: LoRA fold (layer 0) + LN1
__global__ __launch_bounds__(256) void fold_ln_k(
    const float* __restrict__ aw, const float* __restrict__ pw,
    const float* __restrict__ fw, const float* __restrict__ mw,
    const unsigned short* __restrict__ Lb,
    unsigned short* __restrict__ oq, unsigned short* __restrict__ op_,
    unsigned short* __restrict__ of, unsigned short* __restrict__ om,
    const float* __restrict__ hln, const float* __restrict__ lnw,
    const float* __restrict__ lnb, unsigned short* __restrict__ xout) {
  __shared__ char smem[64 * 128 * 2];  // 16KB
  const int tid = threadIdx.x;
  if (blockIdx.x >= 1536) {
    const int row = blockIdx.x - 1536;
    const float* xr = hln + (size_t)row * DD;
    const float4 v = *(const float4*)(xr + tid * 4);
    float s = v.x + v.y + v.z + v.w;
    float ss = v.x * v.x + v.y * v.y + v.z * v.z + v.w * v.w;
#pragma unroll
    for (int off = 32; off > 0; off >>= 1) {
      s += __shfl_down(s, off);
      ss += __shfl_down(ss, off);
    }
    float* red = (float*)smem;
    const int wid = tid >> 6;
    if ((tid & 63) == 0) { red[wid] = s; red[4 + wid] = ss; }
    __syncthreads();
    s = red[0] + red[1] + red[2] + red[3];
    ss = red[4] + red[5] + red[6] + red[7];
    const float mean = s * (1.f / DD);
    const float var = ss * (1.f / DD) - mean * mean;
    const float rstd = rsqrtf(var + 1e-5f);
    const float4 wv = *(const float4*)(lnw + tid * 4);
    const float4 bv = *(const float4*)(lnb + tid * 4);
    ushort4 o;
    o.x = f2bf((v.x - mean) * rstd * wv.x + bv.x);
    o.y = f2bf((v.y - mean) * rstd * wv.y + bv.y);
    o.z = f2bf((v.z - mean) * rstd * wv.z + bv.z);
    o.w = f2bf((v.w - mean) * rstd * wv.w + bv.w);
    *(ushort4*)(xout + (size_t)row * DD + tid * 4) = o;
    return;
  }
  fold_body(blockIdx.x, smem, aw, pw, fw, mw, Lb, oq, op_, of, om);
}

// ---------------------------------------------------------------- unified bf16 MFMA GEMM
template <int BMt, int BNt, int BKt, int MODE>
__global__ __launch_bounds__(256) void gemm_t(const unsigned short* __restrict__ A,
                                              const unsigned short* __restrict__ Wt,
                                              const float* __restrict__ bias,
                                              const float* __restrict__ res,
                                              float* __restrict__ Cf,
                                              unsigned short* __restrict__ Cb,
                                              unsigned short* __restrict__ vt,
                                              int M, int N, int K) {
  constexpr int MI2 = BMt / 32, NJ2 = BNt / 32;
  constexpr int SB = BKt * 2;
  constexpr int SL = BKt / 8;
  constexpr int RC = 1024 / SB;
  constexpr int CAw = BMt / RC / 4;
  constexpr int CBw = BNt / RC / 4;
  __shared__ unsigned short As[BMt * BKt];
  __shared__ unsigned short Bs[BNt * BKt];
  const int tid = threadIdx.x;
  const int w = tid >> 6, l = tid & 63;
  const int gx = gridDim.x;
  const int bid = blockIdx.y * gx + blockIdx.x;
  const int cpx = (gx * gridDim.y) >> 3;
  const int logical = (bid & 7) * cpx + (bid >> 3);
  const int bm = (logical / gx) * BMt, bn = (logical % gx) * BNt;
  const int wr = w >> 1, wc = w & 1;
  const int lr16 = l & 15, lg = l >> 4, l7 = l & 7;
  const int rin = l / SL;
  const int slot = l % SL;
  f32x4 acc[MI2][NJ2] = {};
  for (int k0 = 0; k0 < K; k0 += BKt) {
    __syncthreads();
#pragma unroll
    for (int i = 0; i < CAw; ++i) {
      const int ch = w * CAw + i;
      const int row = ch * RC + rin;
      gload_lds16(A + (size_t)(bm + row) * K + k0 + ((slot ^ (row & 7)) * 8),
                  (char*)As + ch * 1024);
    }
#pragma unroll
    for (int i = 0; i < CBw; ++i) {
      const int ch = w * CBw + i;
      const int row = ch * RC + rin;
      gload_lds16(Wt + (size_t)(bn + row) * K + k0 + ((slot ^ (row & 7)) * 8),
                  (char*)Bs + ch * 1024);
    }
    __syncthreads();
#pragma unroll
    for (int kk = 0; kk < BKt / 32; ++kk) {
      bf16x8 af[MI2], bfr[NJ2];
      const int q = (kk * 4 + lg) ^ l7;
#pragma unroll
      for (int mi = 0; mi < MI2; ++mi)
        af[mi] = *(const bf16x8*)((const char*)As +
            (wr * (BMt / 2) + mi * 16 + lr16) * SB + q * 16);
#pragma unroll
      for (int nj = 0; nj < NJ2; ++nj)
        bfr[nj] = *(const bf16x8*)((const char*)Bs +
            (wc * (BNt / 2) + nj * 16 + lr16) * SB + q * 16);
#pragma unroll
      for (int mi = 0; mi < MI2; ++mi)
#pragma unroll
        for (int nj = 0; nj < NJ2; ++nj)
          acc[mi][nj] = __builtin_amdgcn_mfma_f32_16x16x32_bf16(
              af[mi], bfr[nj], acc[mi][nj], 0, 0, 0);
    }
  }
  const int cr = lg * 4;
  const int cc = lr16;
#pragma unroll
  for (int mi = 0; mi < MI2; ++mi) {
    const int gr0 = bm + wr * (BMt / 2) + mi * 16 + cr;
#pragma unroll
    for (int nj = 0; nj < NJ2; ++nj) {
      const int gc = bn + wc * (BNt / 2) + nj * 16 + cc;
      const float bv = bias[gc];
      if (MODE == 3) {
        if (gc < 2048) {
#pragma unroll
          for (int r = 0; r < 4; ++r)
            Cb[(size_t)(gr0 + r) * 2048 + gc] = f2bf(acc[mi][nj][r] + bv);
        } else {
          const int hv = gc - 2048;
          const int b_ = gr0 >> 10, t0 = gr0 & 1023;
          ushort4 u;
          u.x = f2bf(acc[mi][nj][0] + bv); u.y = f2bf(acc[mi][nj][1] + bv);
          u.z = f2bf(acc[mi][nj][2] + bv); u.w = f2bf(acc[mi][nj][3] + bv);
          *(ushort4*)(vt + ((size_t)(b_ * 1024 + hv)) * 1024 + t0) = u;
        }
      } else if (MODE == 1) {
#pragma unroll
        for (int r = 0; r < 4; ++r) {
          const size_t idx = (size_t)(gr0 + r) * N + gc;
          Cf[idx] = acc[mi][nj][r] + bv + res[idx];
        }
      } else {  // MODE 2
#pragma unroll
        for (int r = 0; r < 4; ++r) {
          float v = acc[mi][nj][r] + bv;
          v = 0.5f * v * (1.f + erff(v * 0.70710678118654752f));
          Cb[(size_t)(gr0 + r) * N + gc] = f2bf(v);
        }
      }
    }
  }
}

// ---------------------------------------------------------------- merged: fc GEMM (gelu) + fold(l+1)
// blocks [0,512): fc <128,128,128,MODE2> M=2048,N=4096,K=1024
// blocks [512,2048): fold for next layer into alternate buffer set
__global__ __launch_bounds__(256) void gemm_fc_fold_k(
    const unsigned short* __restrict__ A, const unsigned short* __restrict__ Wt,
    const float* __restrict__ bias, unsigned short* __restrict__ Cb,
    const float* __restrict__ aw, const float* __restrict__ pw,
    const float* __restrict__ fw, const float* __restrict__ mw,
    const unsigned short* __restrict__ Lb,
    unsigned short* __restrict__ oq, unsigned short* __restrict__ op_,
    unsigned short* __restrict__ of, unsigned short* __restrict__ om) {
  __shared__ char smem[128 * 128 * 2 * 2];  // 64KB (fc); fold uses first 16KB
  const int tid = threadIdx.x;
  if (blockIdx.x >= 512) {
    fold_body(blockIdx.x - 512, smem, aw, pw, fw, mw, Lb, oq, op_, of, om);
    return;
  }
  // ---- fc GEMM path: BM=BN=BK=128, M=2048 N=4096 K=1024
  constexpr int N = 4096, K = 1024;
  unsigned short* As = (unsigned short*)smem;
  unsigned short* Bs = (unsigned short*)(smem + 128 * 128 * 2);
  const int w = tid >> 6, l = tid & 63;
  const int bid = blockIdx.x;
  const int logical = (bid & 7) * 64 + (bid >> 3);  // 512 blocks, 8 XCD chunks of 64
  const int bm = (logical >> 5) * 128, bn = (logical & 31) * 128;
  const int wr = w >> 1, wc = w & 1;
  const int lr16 = l & 15, lg = l >> 4, l7 = l & 7;
  const int rin = l / 16;   // SL=16
  const int slot = l % 16;
  f32x4 acc[4][4] = {};
  for (int k0 = 0; k0 < K; k0 += 128) {
    __syncthreads();
#pragma unroll
    for (int i = 0; i < 8; ++i) {  // CAw=8, RC=4
      const int ch = w * 8 + i;
      const int row = ch * 4 + rin;
      gload_lds16(A + (size_t)(bm + row) * K + k0 + ((slot ^ (row & 7)) * 8),
                  (char*)As + ch * 1024);
    }
#pragma unroll
    for (int i = 0; i < 8; ++i) {
      const int ch = w * 8 + i;
      const int row = ch * 4 + rin;
      gload_lds16(Wt + (size_t)(bn + row) * K + k0 + ((slot ^ (row & 7)) * 8),
                  (char*)Bs + ch * 1024);
    }
    __syncthreads();
#pragma unroll
    for (int kk = 0; kk < 4; ++kk) {
      bf16x8 af[4], bfr[4];
      const int q = (kk * 4 + lg) ^ l7;
#pragma unroll
      for (int mi = 0; mi < 4; ++mi)
        af[mi] = *(const bf16x8*)((const char*)As + (wr * 64 + mi * 16 + lr16) * 256 + q * 16);
#pragma unroll
      for (int nj = 0; nj < 4; ++nj)
        bfr[nj] = *(const bf16x8*)((const char*)Bs + (wc * 64 + nj * 16 + lr16) * 256 + q * 16);
#pragma unroll
      for (int mi = 0; mi < 4; ++mi)
#pragma unroll
        for (int nj = 0; nj < 4; ++nj)
          acc[mi][nj] = __builtin_amdgcn_mfma_f32_16x16x32_bf16(
              af[mi], bfr[nj], acc[mi][nj], 0, 0, 0);
    }
  }
  const int cr = lg * 4;
  const int cc = lr16;
#pragma unroll
  for (int mi = 0; mi < 4; ++mi) {
    const int gr0 = bm + wr * 64 + mi * 16 + cr;
#pragma unroll
    for (int nj = 0; nj < 4; ++nj) {
      const int gc = bn + wc * 64 + nj * 16 + cc;
      const float bv = bias[gc];
#pragma unroll
      for (int r = 0; r < 4; ++r) {
        float v = acc[mi][nj][r] + bv;
        v = 0.5f * v * (1.f + erff(v * 0.70710678118654752f));
        Cb[(size_t)(gr0 + r) * N + gc] = f2bf(v);
      }
    }
  }
}

// ---------------------------------------------------------------- MFMA flash attention, KVBLK=128
#define SM_SCALE_LOG2E 0.18033688011112042f  // log2(e)/8
__global__ __launch_bounds__(256) void attn4_k(const unsigned short* __restrict__ qk,
                                               const unsigned short* __restrict__ vt,
                                               unsigned short* __restrict__ out) {
  const int qt = 15 - blockIdx.x;
  const int bh = blockIdx.y;
  const int b = bh >> 4, hh = bh & 15;
  const int tid = threadIdx.x;
  const int w = tid >> 6, l = tid & 63;
  const int lg = l >> 4;
  const int lr = l & 15;

  __shared__ unsigned short Kt[2][128 * 64];
  __shared__ unsigned short Vb[2][64 * 128];
  __shared__ unsigned short Pb[4][16 * 128];

  bf16x8 qf[2];
  {
    const unsigned short* qp =
        qk + ((size_t)(b * TT + qt * 64 + w * 16 + lr)) * 2048 + hh * 64 + lg * 8;
    qf[0] = *(const bf16x8*)(qp);
    qf[1] = *(const bf16x8*)(qp + 32);
  }
  f32x4 oacc[4] = {};
  float mrow[4] = {-1e30f, -1e30f, -1e30f, -1e30f};
  float lrow[4] = {0.f, 0.f, 0.f, 0.f};

  auto stage = [&](int buf, int kt2) {
#pragma unroll
    for (int i = 0; i < 4; ++i) {
      const int ch = w * 4 + i;
      const int row = ch * 8 + (l >> 3);
      const int sc = ((l & 7) ^ (l >> 3)) * 8;
      const unsigned short* ks =
          qk + ((size_t)(b * TT + kt2 * 128 + row)) * 2048 + 1024 + hh * 64 + sc;
      gload_lds16(ks, (char*)&Kt[buf][0] + ch * 1024);
    }
#pragma unroll
    for (int i = 0; i < 4; ++i) {
      const int ch = w * 4 + i;
      const int row = ch * 4 + (l >> 4);
      const int sc = ((l & 15) ^ (row & 15)) * 8;
      const unsigned short* vs =
          vt + ((size_t)(bh * 64 + row)) * 1024 + kt2 * 128 + sc;
      gload_lds16(vs, (char*)&Vb[buf][0] + ch * 1024);
    }
  };

  const int nkt = (qt >> 1) + 1;
  stage(0, 0);
  int cur = 0;
  unsigned short* Pw = &Pb[w][0];
  const int qlocal = w * 16 + lg * 4;

  for (int kt2 = 0; kt2 < nkt; ++kt2) {
    __syncthreads();
    if (kt2 + 1 < nkt) stage(cur ^ 1, kt2 + 1);
    const unsigned short* Kb_ = &Kt[cur][0];
    const unsigned short* Vb_ = &Vb[cur][0];
    const bool last = (kt2 == nkt - 1);

    f32x4 s[8];
    __builtin_amdgcn_s_setprio(1);
#pragma unroll
    for (int j = 0; j < 8; ++j) {
      f32x4 sj = {};
#pragma unroll
      for (int ks = 0; ks < 2; ++ks) {
        const bf16x8 kf = *(const bf16x8*)((const char*)Kb_ + (j * 16 + lr) * 128 +
                                           (((ks * 4 + lg) ^ (lr & 7)) * 16));
        sj = __builtin_amdgcn_mfma_f32_16x16x32_bf16(qf[ks], kf, sj, 0, 0, 0);
      }
      s[j] = sj;
    }
    __builtin_amdgcn_s_setprio(0);

#pragma unroll
    for (int j = 0; j < 8; ++j)
#pragma unroll
      for (int r = 0; r < 4; ++r) {
        float v = s[j][r] * SM_SCALE_LOG2E;
        if (last && (kt2 * 128 + j * 16 + lr > qt * 64 + qlocal + r)) v = -1e30f;
        s[j][r] = v;
      }
    float corr[4];
#pragma unroll
    for (int r = 0; r < 4; ++r) {
      float mx = s[0][r];
#pragma unroll
      for (int j = 1; j < 8; ++j) mx = fmaxf(mx, s[j][r]);
      mx = fmaxf(mx, __shfl_xor(mx, 1));
      mx = fmaxf(mx, __shfl_xor(mx, 2));
      mx = fmaxf(mx, __shfl_xor(mx, 4));
      mx = fmaxf(mx, __shfl_xor(mx, 8));
      const float mn = fmaxf(mrow[r], mx);
      corr[r] = exp2f(mrow[r] - mn);
      mrow[r] = mn;
      lrow[r] *= corr[r];
    }
#pragma unroll
    for (int dt = 0; dt < 4; ++dt) {
      oacc[dt][0] *= corr[0]; oacc[dt][1] *= corr[1];
      oacc[dt][2] *= corr[2]; oacc[dt][3] *= corr[3];
    }
#pragma unroll
    for (int j = 0; j < 8; ++j)
#pragma unroll
      for (int r = 0; r < 4; ++r) {
        const float p = exp2f(s[j][r] - mrow[r]);
        lrow[r] += p;
        const int q = lg * 4 + r;
        const int kv = j * 16 + lr;
        *(unsigned short*)((char*)Pw + q * 256 + ((kv * 2) ^ ((q & 15) << 4))) = f2bf(p);
      }
    asm volatile("s_waitcnt lgkmcnt(0)" ::: "memory");
    __builtin_amdgcn_sched_barrier(0);

    __builtin_amdgcn_s_setprio(1);
#pragma unroll
    for (int ks = 0; ks < 4; ++ks) {
      const bf16x8 pf = *(const bf16x8*)((const char*)Pw + lr * 256 +
                                         (((ks * 4 + lg) ^ (lr & 15)) * 16));
#pragma unroll
      for (int dt = 0; dt < 4; ++dt) {
        const bf16x8 vf = *(const bf16x8*)((const char*)Vb_ + (dt * 16 + lr) * 256 +
                                           (((ks * 4 + lg) ^ (lr & 15)) * 16));
        oacc[dt] = __builtin_amdgcn_mfma_f32_16x16x32_bf16(pf, vf, oacc[dt], 0, 0, 0);
      }
    }
    __builtin_amdgcn_s_setprio(0);
    cur ^= 1;
  }

#pragma unroll
  for (int r = 0; r < 4; ++r) {
    float lv = lrow[r];
    lv += __shfl_xor(lv, 1);
    lv += __shfl_xor(lv, 2);
    lv += __shfl_xor(lv, 4);
    lv += __shfl_xor(lv, 8);
    lrow[r] = 1.f / lv;
  }
  unsigned short* ob = out + ((size_t)(b * TT + qt * 64 + w * 16 + lg * 4)) * 1024 + hh * 64 + lr;
#pragma unroll
  for (int r = 0; r < 4; ++r)
#pragma unroll
    for (int dt = 0; dt < 4; ++dt)
      ob[(size_t)r * 1024 + dt * 16] = f2bf(oacc[dt][r] * lrow[r]);
}

// ---------------------------------------------------------------- host
extern "C" void kernel_launch(void* const* d_in, const int* in_sizes, int n_in,
                              void* d_out, int out_size, void* d_ws, size_t ws_size,
                              hipStream_t stream) {
  (void)in_sizes; (void)n_in; (void)out_size; (void)ws_size;
  const int* ids = (const int*)d_in[0];
  const float* wte = (const float*)d_in[1];
  const float* wpe = (const float*)d_in[2];
  const float* ln1w = (const float*)d_in[3];
  const float* ln1b = (const float*)d_in[4];
  const float* attnw = (const float*)d_in[5];
  const float* attnb = (const float*)d_in[6];
  const float* attnla = (const float*)d_in[7];
  const float* attnlb = (const float*)d_in[8];
  const float* projw = (const float*)d_in[9];
  const float* projb = (const float*)d_in[10];
  const float* projla = (const float*)d_in[11];
  const float* projlb = (const float*)d_in[12];
  const float* ln2w = (const float*)d_in[13];
  const float* ln2b = (const float*)d_in[14];
  const float* fcw = (const float*)d_in[15];
  const float* fcb = (const float*)d_in[16];
  const float* fcla = (const float*)d_in[17];
  const float* fclb = (const float*)d_in[18];
  const float* mpw = (const float*)d_in[19];
  const float* mpb = (const float*)d_in[20];
  const float* mpla = (const float*)d_in[21];
  const float* mplb = (const float*)d_in[22];
  const float* lnfw = (const float*)d_in[23];
  const float* lnfb = (const float*)d_in[24];

  char* ws = (char*)d_ws;
  float* h = (float*)ws;                        ws += (size_t)MM * DD * 4;       // 8MB
  unsigned short* x = (unsigned short*)ws;      ws += (size_t)MM * DD * 2;       // 4MB
  unsigned short* qkb = (unsigned short*)ws;    ws += (size_t)MM * 2 * DD * 2;   // 8MB
  unsigned short* vtb = (unsigned short*)ws;    ws += (size_t)MM * DD * 2;       // 4MB
  unsigned short* ho = (unsigned short*)ws;     ws += (size_t)MM * DD * 2;       // 4MB
  unsigned short* hm = (unsigned short*)ws;     ws += (size_t)MM * 4 * DD * 2;   // 16MB
  unsigned short* wqkvB[2], *wprojB[2], *wfcB[2], *wmpB[2];
  for (int p = 0; p < 2; ++p) {
    wqkvB[p] = (unsigned short*)ws; ws += (size_t)3 * DD * DD * 2;   // 6MB
    wprojB[p] = (unsigned short*)ws; ws += (size_t)DD * DD * 2;      // 2MB
    wfcB[p] = (unsigned short*)ws;  ws += (size_t)4 * DD * DD * 2;   // 8MB
    wmpB[p] = (unsigned short*)ws;  ws += (size_t)DD * 4 * DD * 2;   // 8MB
  }
  unsigned short* loraP = (unsigned short*)ws;  ws += (size_t)NL * 16384 * 32 * 2;  // 12.6MB

  hipLaunchKernelGGL(embed_cvt_k, dim3(MM * DD / 256 + NL * 16384 * 32 / 256), dim3(256),
                     0, stream, ids, wte, wpe, h,
                     attnla, attnlb, projla, projlb, fcla, fclb, mpla, mplb, loraP);

  for (int l = 0; l < NL; ++l) {
    const int p = l & 1, pn = (l + 1) & 1;
    const float* ab = attnb + (size_t)l * 3 * DD;
    const float* pb = projb + (size_t)l * DD;
    const float* fb = fcb + (size_t)l * 4 * DD;
    const float* mb = mpb + (size_t)l * DD;

    if (l == 0) {
      // fold(0) + LN1(0) merged
      hipLaunchKernelGGL(fold_ln_k, dim3(1536 + MM), dim3(256), 0, stream,
                         attnw, projw, fcw, mpw, loraP,
                         wqkvB[0], wprojB[0], wfcB[0], wmpB[0],
                         h, ln1w, ln1b, x);
    } else {
      hipLaunchKernelGGL(ln_bf_k, dim3(MM), dim3(256), 0, stream, h,
                         ln1w + (size_t)l * DD, ln1b + (size_t)l * DD, x);
    }

    hipLaunchKernelGGL((gemm_t<128, 64, 128, 3>), dim3(3 * DD / 64, MM / 128), dim3(256), 0,
                       stream, x, wqkvB[p], ab, (const float*)nullptr, (float*)nullptr,
                       qkb, vtb, MM, 3 * DD, DD);
    hipLaunchKernelGGL(attn4_k, dim3(TT / 64, NB * NH), dim3(256), 0, stream, qkb, vtb, ho);
    hipLaunchKernelGGL((gemm_t<64, 64, 256, 1>), dim3(DD / 64, MM / 64), dim3(256), 0,
                       stream, ho, wprojB[p], pb, h, h, (unsigned short*)nullptr,
                       (unsigned short*)nullptr, MM, DD, DD);
    hipLaunchKernelGGL(ln_bf_k, dim3(MM), dim3(256), 0, stream, h,
                       ln2w + (size_t)l * DD, ln2b + (size_t)l * DD, x);

    if (l + 1 < NL) {
      // fc GEMM || fold(l+1) into buffer set pn
      hipLaunchKernelGGL(gemm_fc_fold_k, dim3(512 + 1536), dim3(256), 0, stream,
                         x, wfcB[p], fb, hm,
                         attnw + (size_t)(l + 1) * 3 * DD * DD,
                         projw + (size_t)(l + 1) * DD * DD,
                         fcw + (size_t)(l + 1) * 4 * DD * DD,
                         mpw + (size_t)(l + 1) * DD * 4 * DD,
                         loraP + (size_t)(l + 1) * 16384 * 32,
                         wqkvB[pn], wprojB[pn], wfcB[pn], wmpB[pn]);
    } else {
      hipLaunchKernelGGL((gemm_t<128, 128, 128, 2>), dim3(4 * DD / 128, MM / 128), dim3(256),
                         0, stream, x, wfcB[p], fb, (const float*)nullptr, (float*)nullptr,
                         hm, (unsigned short*)nullptr, MM, 4 * DD, DD);
    }

    hipLaunchKernelGGL((gemm_t<64, 64, 256, 1>), dim3(DD / 64, MM / 64), dim3(256), 0,
                       stream, hm, wmpB[p], mb, h, h, (unsigned short*)nullptr,
                       (unsigned short*)nullptr, MM, DD, 4 * DD);
  }

  hipLaunchKernelGGL(ln_f_k, dim3(MM), dim3(256), 0, stream, h, lnfw, lnfb, (float*)d_out);
}

// Round 16
// 1723.576 us; speedup vs baseline: 1.0391x; 1.0391x over previous
//
#include <hip/hip_runtime.h>
#include <math.h>

#define TT 1024
#define DD 1024
#define NH 16
#define NB 2
#define NL 12
#define RR 32
#define MM (NB * TT)  // 2048

typedef __attribute__((ext_vector_type(8))) short bf16x8;
typedef __attribute__((ext_vector_type(4))) float f32x4;

__device__ __forceinline__ unsigned short f2bf(float f) {
  unsigned int u = __float_as_uint(f);
  u = (u + 0x7FFFu + ((u >> 16) & 1u)) >> 16;
  return (unsigned short)u;
}
__device__ __forceinline__ float bf2f(unsigned short u) {
  return __uint_as_float((unsigned int)u << 16);
}

typedef __attribute__((address_space(1))) void gvoid;
typedef __attribute__((address_space(3))) void lvoid;
__device__ __forceinline__ void gload_lds16(const void* g, void* l) {
  __builtin_amdgcn_global_load_lds((gvoid*)g, (lvoid*)l, 16, 0, 0);
}

// ---------------------------------------------------------------- embed + LoRA cvt (merged, independent)
__global__ __launch_bounds__(256) void embed_cvt_k(
    const int* __restrict__ ids, const float* __restrict__ wte,
    const float* __restrict__ wpe, float* __restrict__ h,
    const float* __restrict__ ala, const float* __restrict__ alb,
    const float* __restrict__ pla, const float* __restrict__ plb,
    const float* __restrict__ fla, const float* __restrict__ flb,
    const float* __restrict__ mla, const float* __restrict__ mlb,
    unsigned short* __restrict__ out) {
  if (blockIdx.x < MM * DD / 256) {
    const int i = blockIdx.x * 256 + threadIdx.x;
    const int row = i >> 10;
    const int d = i & 1023;
    const int t = row & (TT - 1);
    const int id = ids[row];
    h[i] = wte[(size_t)id * DD + d] + wpe[(size_t)t * DD + d];
    return;
  }
  const int g = (blockIdx.x - MM * DD / 256) * 256 + threadIdx.x;  // over NL*16384*32
  const int layer = g >> 19;
  const int rem = g & 524287;
  const int row = rem >> 5;
  const int r = rem & 31;
  float v;
  if (row < 1024)       v = ala[(size_t)layer * 32 * 1024 + r * 1024 + row];
  else if (row < 4096)  v = alb[(size_t)layer * 3072 * 32 + (row - 1024) * 32 + r];
  else if (row < 5120)  v = pla[(size_t)layer * 32 * 1024 + r * 1024 + (row - 4096)];
  else if (row < 6144)  v = plb[(size_t)layer * 1024 * 32 + (row - 5120) * 32 + r];
  else if (row < 7168)  v = fla[(size_t)layer * 32 * 1024 + r * 1024 + (row - 6144)];
  else if (row < 11264) v = flb[(size_t)layer * 4096 * 32 + (row - 7168) * 32 + r];
  else if (row < 15360) v = mla[(size_t)layer * 32 * 4096 + r * 4096 + (row - 11264)];
  else                  v = mlb[(size_t)layer * 1024 * 32 + (row - 15360) * 32 + r];
  out[g] = f2bf(v);
}

// ---------------------------------------------------------------- layernorm (fp32 in, bf16 out)
__global__ __launch_bounds__(256) void ln_bf_k(const float* __restrict__ x,
                                               const float* __restrict__ w,
                                               const float* __restrict__ b,
                                               unsigned short* __restrict__ out) {
  const int row = blockIdx.x;
  const float* xr = x + (size_t)row * DD;
  const float4 v = *(const float4*)(xr + threadIdx.x * 4);
  float s = v.x + v.y + v.z + v.w;
  float ss = v.x * v.x + v.y * v.y + v.z * v.z + v.w * v.w;
#pragma unroll
  for (int off = 32; off > 0; off >>= 1) {
    s += __shfl_down(s, off);
    ss += __shfl_down(ss, off);
  }
  __shared__ float rs[4], rss[4];
  const int wid = threadIdx.x >> 6;
  if ((threadIdx.x & 63) == 0) { rs[wid] = s; rss[wid] = ss; }
  __syncthreads();
  s = rs[0] + rs[1] + rs[2] + rs[3];
  ss = rss[0] + rss[1] + rss[2] + rss[3];
  const float mean = s * (1.f / DD);
  const float var = ss * (1.f / DD) - mean * mean;
  const float rstd = rsqrtf(var + 1e-5f);
  const float4 wv = *(const float4*)(w + threadIdx.x * 4);
  const float4 bv = *(const float4*)(b + threadIdx.x * 4);
  ushort4 o;
  o.x = f2bf((v.x - mean) * rstd * wv.x + bv.x);
  o.y = f2bf((v.y - mean) * rstd * wv.y + bv.y);
  o.z = f2bf((v.z - mean) * rstd * wv.z + bv.z);
  o.w = f2bf((v.w - mean) * rstd * wv.w + bv.w);
  *(ushort4*)(out + (size_t)row * DD + threadIdx.x * 4) = o;
}

// final layernorm fp32 out
__global__ __launch_bounds__(256) void ln_f_k(const float* __restrict__ x,
                                              const float* __restrict__ w,
                                              const float* __restrict__ b,
                                              float* __restrict__ out) {
  const int row = blockIdx.x;
  const float* xr = x + (size_t)row * DD;
  const float4 v = *(const float4*)(xr + threadIdx.x * 4);
  float s = v.x + v.y + v.z + v.w;
  float ss = v.x * v.x + v.y * v.y + v.z * v.z + v.w * v.w;
#pragma unroll
  for (int off = 32; off > 0; off >>= 1) {
    s += __shfl_down(s, off);
    ss += __shfl_down(ss, off);
  }
  __shared__ float rs[4], rss[4];
  const int wid = threadIdx.x >> 6;
  if ((threadIdx.x & 63) == 0) { rs[wid] = s; rss[wid] = ss; }
  __syncthreads();
  s = rs[0] + rs[1] + rs[2] + rs[3];
  ss = rss[0] + rss[1] + rss[2] + rss[3];
  const float mean = s * (1.f / DD);
  const float var = ss * (1.f / DD) - mean * mean;
  const float rstd = rsqrtf(var + 1e-5f);
  const float4 wv = *(const float4*)(w + threadIdx.x * 4);
  const float4 bv = *(const float4*)(b + threadIdx.x * 4);
  float4 o;
  o.x = (v.x - mean) * rstd * wv.x + bv.x;
  o.y = (v.y - mean) * rstd * wv.y + bv.y;
  o.z = (v.z - mean) * rstd * wv.z + bv.z;
  o.w = (v.w - mean) * rstd * wv.w + bv.w;
  *(float4*)(out + (size_t)row * DD + threadIdx.x * 4) = o;
}

// ---------------------------------------------------------------- merged: LoRA fold (per-layer JIT) + LN1
__global__ __launch_bounds__(256) void fold_ln_k(
    const float* __restrict__ aw, const float* __restrict__ pw,
    const float* __restrict__ fw, const float* __restrict__ mw,
    const unsigned short* __restrict__ Lb,
    unsigned short* __restrict__ oq, unsigned short* __restrict__ op_,
    unsigned short* __restrict__ of, unsigned short* __restrict__ om,
    const float* __restrict__ hln, const float* __restrict__ lnw,
    const float* __restrict__ lnb, unsigned short* __restrict__ xout) {
  __shared__ unsigned short dl[64 * 128];  // 16KB (fold); LN reuses first 32B
  const int tid = threadIdx.x;
  if (blockIdx.x >= 1536) {
    const int row = blockIdx.x - 1536;
    const float* xr = hln + (size_t)row * DD;
    const float4 v = *(const float4*)(xr + tid * 4);
    float s = v.x + v.y + v.z + v.w;
    float ss = v.x * v.x + v.y * v.y + v.z * v.z + v.w * v.w;
#pragma unroll
    for (int off = 32; off > 0; off >>= 1) {
      s += __shfl_down(s, off);
      ss += __shfl_down(ss, off);
    }
    float* red = (float*)dl;
    const int wid = tid >> 6;
    if ((tid & 63) == 0) { red[wid] = s; red[4 + wid] = ss; }
    __syncthreads();
    s = red[0] + red[1] + red[2] + red[3];
    ss = red[4] + red[5] + red[6] + red[7];
    const float mean = s * (1.f / DD);
    const float var = ss * (1.f / DD) - mean * mean;
    const float rstd = rsqrtf(var + 1e-5f);
    const float4 wv = *(const float4*)(lnw + tid * 4);
    const float4 bv = *(const float4*)(lnb + tid * 4);
    ushort4 o;
    o.x = f2bf((v.x - mean) * rstd * wv.x + bv.x);
    o.y = f2bf((v.y - mean) * rstd * wv.y + bv.y);
    o.z = f2bf((v.z - mean) * rstd * wv.z + bv.z);
    o.w = f2bf((v.w - mean) * rstd * wv.w + bv.w);
    *(ushort4*)(xout + (size_t)row * DD + tid * 4) = o;
    return;
  }
  const int lid = blockIdx.x;  // 0..1535
  const float* W;
  unsigned short* out;
  const unsigned short *Bl, *Al;
  int K, n0, kblk;
  if (lid < 384) {
    W = aw; out = oq; Bl = Lb + 1024 * 32; Al = Lb;
    K = DD; n0 = (lid >> 3) * 64; kblk = (lid & 7) * 128;
  } else if (lid < 512) {
    const int t = lid - 384;
    W = pw; out = op_; Bl = Lb + 5120 * 32; Al = Lb + 4096 * 32;
    K = DD; n0 = (t >> 3) * 64; kblk = (t & 7) * 128;
  } else if (lid < 1024) {
    const int t = lid - 512;
    W = fw; out = of; Bl = Lb + 7168 * 32; Al = Lb + 6144 * 32;
    K = DD; n0 = (t >> 3) * 64; kblk = (t & 7) * 128;
  } else {
    const int t = lid - 1024;
    W = mw; out = om; Bl = Lb + 15360 * 32; Al = Lb + 11264 * 32;
    K = 4 * DD; n0 = (t >> 5) * 64; kblk = (t & 31) * 128;
  }
  const int w = tid >> 6, l = tid & 63;
  const int lr16 = l & 15, lg = l >> 4;
  const int nloc = w * 16 + lr16;
  const bf16x8 bfrag = *(const bf16x8*)(Bl + (size_t)(n0 + nloc) * 32 + lg * 8);
#pragma unroll
  for (int kc = 0; kc < 8; ++kc) {
    const bf16x8 afr = *(const bf16x8*)(Al + (size_t)(kblk + kc * 16 + lr16) * 32 + lg * 8);
    f32x4 acc = {};
    acc = __builtin_amdgcn_mfma_f32_16x16x32_bf16(afr, bfrag, acc, 0, 0, 0);
    ushort4 dv;
    dv.x = f2bf(2.f * acc[0]); dv.y = f2bf(2.f * acc[1]);
    dv.z = f2bf(2.f * acc[2]); dv.w = f2bf(2.f * acc[3]);
    const unsigned int byte = ((unsigned)(nloc * 256 + kc * 32 + lg * 8)) ^
                              (((unsigned)nloc & 3u) << 5);
    *(ushort4*)((char*)dl + byte) = dv;
  }
  __syncthreads();
  float4 wv[8];
#pragma unroll
  for (int it = 0; it < 8; ++it) {
    const int flat = it * 1024 + tid * 4;
    const int row = flat >> 7;
    const int k = flat & 127;
    wv[it] = *(const float4*)(W + (size_t)(n0 + row) * K + kblk + k);
  }
  asm volatile("s_waitcnt vmcnt(0)" ::: "memory");
#pragma unroll
  for (int it = 0; it < 8; ++it) {
    const int flat = it * 1024 + tid * 4;
    const int row = flat >> 7;
    const int k = flat & 127;
    const unsigned int byte = ((unsigned)(row * 256 + k * 2)) ^
                              (((unsigned)row & 3u) << 5);
    const ushort4 dv = *(const ushort4*)((const char*)dl + byte);
    ushort4 o;
    o.x = f2bf(wv[it].x + bf2f(dv.x));
    o.y = f2bf(wv[it].y + bf2f(dv.y));
    o.z = f2bf(wv[it].z + bf2f(dv.z));
    o.w = f2bf(wv[it].w + bf2f(dv.w));
    *(ushort4*)(out + (size_t)(n0 + row) * K + kblk + k) = o;
  }
}

// ---------------------------------------------------------------- unified bf16 MFMA GEMM
template <int BMt, int BNt, int BKt, int MODE>
__global__ __launch_bounds__(256) void gemm_t(const unsigned short* __restrict__ A,
                                              const unsigned short* __restrict__ Wt,
                                              const float* __restrict__ bias,
                                              const float* __restrict__ res,
                                              float* __restrict__ Cf,
                                              unsigned short* __restrict__ Cb,
                                              unsigned short* __restrict__ vt,
                                              int M, int N, int K) {
  constexpr int MI2 = BMt / 32, NJ2 = BNt / 32;
  constexpr int SB = BKt * 2;
  constexpr int SL = BKt / 8;
  constexpr int RC = 1024 / SB;
  constexpr int CAw = BMt / RC / 4;
  constexpr int CBw = BNt / RC / 4;
  __shared__ unsigned short As[BMt * BKt];
  __shared__ unsigned short Bs[BNt * BKt];
  const int tid = threadIdx.x;
  const int w = tid >> 6, l = tid & 63;
  const int gx = gridDim.x;
  const int bid = blockIdx.y * gx + blockIdx.x;
  const int cpx = (gx * gridDim.y) >> 3;
  const int logical = (bid & 7) * cpx + (bid >> 3);
  const int bm = (logical / gx) * BMt, bn = (logical % gx) * BNt;
  const int wr = w >> 1, wc = w & 1;
  const int lr16 = l & 15, lg = l >> 4, l7 = l & 7;
  const int rin = l / SL;
  const int slot = l % SL;
  f32x4 acc[MI2][NJ2] = {};
  for (int k0 = 0; k0 < K; k0 += BKt) {
    __syncthreads();
#pragma unroll
    for (int i = 0; i < CAw; ++i) {
      const int ch = w * CAw + i;
      const int row = ch * RC + rin;
      gload_lds16(A + (size_t)(bm + row) * K + k0 + ((slot ^ (row & 7)) * 8),
                  (char*)As + ch * 1024);
    }
#pragma unroll
    for (int i = 0; i < CBw; ++i) {
      const int ch = w * CBw + i;
      const int row = ch * RC + rin;
      gload_lds16(Wt + (size_t)(bn + row) * K + k0 + ((slot ^ (row & 7)) * 8),
                  (char*)Bs + ch * 1024);
    }
    __syncthreads();
#pragma unroll
    for (int kk = 0; kk < BKt / 32; ++kk) {
      bf16x8 af[MI2], bfr[NJ2];
      const int q = (kk * 4 + lg) ^ l7;
#pragma unroll
      for (int mi = 0; mi < MI2; ++mi)
        af[mi] = *(const bf16x8*)((const char*)As +
            (wr * (BMt / 2) + mi * 16 + lr16) * SB + q * 16);
#pragma unroll
      for (int nj = 0; nj < NJ2; ++nj)
        bfr[nj] = *(const bf16x8*)((const char*)Bs +
            (wc * (BNt / 2) + nj * 16 + lr16) * SB + q * 16);
#pragma unroll
      for (int mi = 0; mi < MI2; ++mi)
#pragma unroll
        for (int nj = 0; nj < NJ2; ++nj)
          acc[mi][nj] = __builtin_amdgcn_mfma_f32_16x16x32_bf16(
              af[mi], bfr[nj], acc[mi][nj], 0, 0, 0);
    }
  }
  const int cr = lg * 4;
  const int cc = lr16;
#pragma unroll
  for (int mi = 0; mi < MI2; ++mi) {
    const int gr0 = bm + wr * (BMt / 2) + mi * 16 + cr;
#pragma unroll
    for (int nj = 0; nj < NJ2; ++nj) {
      const int gc = bn + wc * (BNt / 2) + nj * 16 + cc;
      const float bv = bias[gc];
      if (MODE == 3) {
        if (gc < 2048) {
#pragma unroll
          for (int r = 0; r < 4; ++r)
            Cb[(size_t)(gr0 + r) * 2048 + gc] = f2bf(acc[mi][nj][r] + bv);
        } else {
          const int hv = gc - 2048;
          const int b_ = gr0 >> 10, t0 = gr0 & 1023;
          ushort4 u;
          u.x = f2bf(acc[mi][nj][0] + bv); u.y = f2bf(acc[mi][nj][1] + bv);
          u.z = f2bf(acc[mi][nj][2] + bv); u.w = f2bf(acc[mi][nj][3] + bv);
          *(ushort4*)(vt + ((size_t)(b_ * 1024 + hv)) * 1024 + t0) = u;
        }
      } else if (MODE == 1) {
#pragma unroll
        for (int r = 0; r < 4; ++r) {
          const size_t idx = (size_t)(gr0 + r) * N + gc;
          Cf[idx] = acc[mi][nj][r] + bv + res[idx];
        }
      } else {  // MODE 2
#pragma unroll
        for (int r = 0; r < 4; ++r) {
          float v = acc[mi][nj][r] + bv;
          v = 0.5f * v * (1.f + erff(v * 0.70710678118654752f));
          Cb[(size_t)(gr0 + r) * N + gc] = f2bf(v);
        }
      }
    }
  }
}

// ---------------------------------------------------------------- MFMA flash attention, KVBLK=128
// XCD-clustered: all 16 qt-tiles of a bh land on one XCD (K/V fetched once per XCD L2).
#define SM_SCALE_LOG2E 0.18033688011112042f  // log2(e)/8
__global__ __launch_bounds__(256) void attn4_k(const unsigned short* __restrict__ qk,
                                               const unsigned short* __restrict__ vt,
                                               unsigned short* __restrict__ out) {
  const int i = blockIdx.y * 16 + blockIdx.x;      // flat id, 512 blocks
  const int bh = (i & 7) + ((i >> 7) << 3);        // XCD (i&7) handles 4 bh values
  const int qt = 15 - ((i >> 3) & 15);             // heavy tiles first within XCD
  const int b = bh >> 4, hh = bh & 15;
  const int tid = threadIdx.x;
  const int w = tid >> 6, l = tid & 63;
  const int lg = l >> 4;
  const int lr = l & 15;

  __shared__ unsigned short Kt[2][128 * 64];
  __shared__ unsigned short Vb[2][64 * 128];
  __shared__ unsigned short Pb[4][16 * 128];

  bf16x8 qf[2];
  {
    const unsigned short* qp =
        qk + ((size_t)(b * TT + qt * 64 + w * 16 + lr)) * 2048 + hh * 64 + lg * 8;
    qf[0] = *(const bf16x8*)(qp);
    qf[1] = *(const bf16x8*)(qp + 32);
  }
  f32x4 oacc[4] = {};
  float mrow[4] = {-1e30f, -1e30f, -1e30f, -1e30f};
  float lrow[4] = {0.f, 0.f, 0.f, 0.f};

  auto stage = [&](int buf, int kt2) {
#pragma unroll
    for (int i2 = 0; i2 < 4; ++i2) {
      const int ch = w * 4 + i2;
      const int row = ch * 8 + (l >> 3);
      const int sc = ((l & 7) ^ (l >> 3)) * 8;
      const unsigned short* ks =
          qk + ((size_t)(b * TT + kt2 * 128 + row)) * 2048 + 1024 + hh * 64 + sc;
      gload_lds16(ks, (char*)&Kt[buf][0] + ch * 1024);
    }
#pragma unroll
    for (int i2 = 0; i2 < 4; ++i2) {
      const int ch = w * 4 + i2;
      const int row = ch * 4 + (l >> 4);
      const int sc = ((l & 15) ^ (row & 15)) * 8;
      const unsigned short* vs =
          vt + ((size_t)(bh * 64 + row)) * 1024 + kt2 * 128 + sc;
      gload_lds16(vs, (char*)&Vb[buf][0] + ch * 1024);
    }
  };

  const int nkt = (qt >> 1) + 1;
  stage(0, 0);
  int cur = 0;
  unsigned short* Pw = &Pb[w][0];
  const int qlocal = w * 16 + lg * 4;

  for (int kt2 = 0; kt2 < nkt; ++kt2) {
    __syncthreads();
    if (kt2 + 1 < nkt) stage(cur ^ 1, kt2 + 1);
    const unsigned short* Kb_ = &Kt[cur][0];
    const unsigned short* Vb_ = &Vb[cur][0];
    const bool last = (kt2 == nkt - 1);

    f32x4 s[8];
    __builtin_amdgcn_s_setprio(1);
#pragma unroll
    for (int j = 0; j < 8; ++j) {
      f32x4 sj = {};
#pragma unroll
      for (int ks = 0; ks < 2; ++ks) {
        const bf16x8 kf = *(const bf16x8*)((const char*)Kb_ + (j * 16 + lr) * 128 +
                                           (((ks * 4 + lg) ^ (lr & 7)) * 16));
        sj = __builtin_amdgcn_mfma_f32_16x16x32_bf16(qf[ks], kf, sj, 0, 0, 0);
      }
      s[j] = sj;
    }
    __builtin_amdgcn_s_setprio(0);

#pragma unroll
    for (int j = 0; j < 8; ++j)
#pragma unroll
      for (int r = 0; r < 4; ++r) {
        float v = s[j][r] * SM_SCALE_LOG2E;
        if (last && (kt2 * 128 + j * 16 + lr > qt * 64 + qlocal + r)) v = -1e30f;
        s[j][r] = v;
      }
    float corr[4];
#pragma unroll
    for (int r = 0; r < 4; ++r) {
      float mx = s[0][r];
#pragma unroll
      for (int j = 1; j < 8; ++j) mx = fmaxf(mx, s[j][r]);
      mx = fmaxf(mx, __shfl_xor(mx, 1));
      mx = fmaxf(mx, __shfl_xor(mx, 2));
      mx = fmaxf(mx, __shfl_xor(mx, 4));
      mx = fmaxf(mx, __shfl_xor(mx, 8));
      const float mn = fmaxf(mrow[r], mx);
      corr[r] = exp2f(mrow[r] - mn);
      mrow[r] = mn;
      lrow[r] *= corr[r];
    }
#pragma unroll
    for (int dt = 0; dt < 4; ++dt) {
      oacc[dt][0] *= corr[0]; oacc[dt][1] *= corr[1];
      oacc[dt][2] *= corr[2]; oacc[dt][3] *= corr[3];
    }
#pragma unroll
    for (int j = 0; j < 8; ++j)
#pragma unroll
      for (int r = 0; r < 4; ++r) {
        const float p = exp2f(s[j][r] - mrow[r]);
        lrow[r] += p;
        const int q = lg * 4 + r;
        const int kv = j * 16 + lr;
        *(unsigned short*)((char*)Pw + q * 256 + ((kv * 2) ^ ((q & 15) << 4))) = f2bf(p);
      }
    asm volatile("s_waitcnt lgkmcnt(0)" ::: "memory");
    __builtin_amdgcn_sched_barrier(0);

    __builtin_amdgcn_s_setprio(1);
#pragma unroll
    for (int ks = 0; ks < 4; ++ks) {
      const bf16x8 pf = *(const bf16x8*)((const char*)Pw + lr * 256 +
                                         (((ks * 4 + lg) ^ (lr & 15)) * 16));
#pragma unroll
      for (int dt = 0; dt < 4; ++dt) {
        const bf16x8 vf = *(const bf16x8*)((const char*)Vb_ + (dt * 16 + lr) * 256 +
                                           (((ks * 4 + lg) ^ (lr & 15)) * 16));
        oacc[dt] = __builtin_amdgcn_mfma_f32_16x16x32_bf16(pf, vf, oacc[dt], 0, 0, 0);
      }
    }
    __builtin_amdgcn_s_setprio(0);
    cur ^= 1;
  }

#pragma unroll
  for (int r = 0; r < 4; ++r) {
    float lv = lrow[r];
    lv += __shfl_xor(lv, 1);
    lv += __shfl_xor(lv, 2);
    lv += __shfl_xor(lv, 4);
    lv += __shfl_xor(lv, 8);
    lrow[r] = 1.f / lv;
  }
  unsigned short* ob = out + ((size_t)(b * TT + qt * 64 + w * 16 + lg * 4)) * 1024 + hh * 64 + lr;
#pragma unroll
  for (int r = 0; r < 4; ++r)
#pragma unroll
    for (int dt = 0; dt < 4; ++dt)
      ob[(size_t)r * 1024 + dt * 16] = f2bf(oacc[dt][r] * lrow[r]);
}

// ---------------------------------------------------------------- host
extern "C" void kernel_launch(void* const* d_in, const int* in_sizes, int n_in,
                              void* d_out, int out_size, void* d_ws, size_t ws_size,
                              hipStream_t stream) {
  (void)in_sizes; (void)n_in; (void)out_size; (void)ws_size;
  const int* ids = (const int*)d_in[0];
  const float* wte = (const float*)d_in[1];
  const float* wpe = (const float*)d_in[2];
  const float* ln1w = (const float*)d_in[3];
  const float* ln1b = (const float*)d_in[4];
  const float* attnw = (const float*)d_in[5];
  const float* attnb = (const float*)d_in[6];
  const float* attnla = (const float*)d_in[7];
  const float* attnlb = (const float*)d_in[8];
  const float* projw = (const float*)d_in[9];
  const float* projb = (const float*)d_in[10];
  const float* projla = (const float*)d_in[11];
  const float* projlb = (const float*)d_in[12];
  const float* ln2w = (const float*)d_in[13];
  const float* ln2b = (const float*)d_in[14];
  const float* fcw = (const float*)d_in[15];
  const float* fcb = (const float*)d_in[16];
  const float* fcla = (const float*)d_in[17];
  const float* fclb = (const float*)d_in[18];
  const float* mpw = (const float*)d_in[19];
  const float* mpb = (const float*)d_in[20];
  const float* mpla = (const float*)d_in[21];
  const float* mplb = (const float*)d_in[22];
  const float* lnfw = (const float*)d_in[23];
  const float* lnfb = (const float*)d_in[24];

  char* ws = (char*)d_ws;
  float* h = (float*)ws;                        ws += (size_t)MM * DD * 4;       // 8MB
  unsigned short* x = (unsigned short*)ws;      ws += (size_t)MM * DD * 2;       // 4MB
  unsigned short* qkb = (unsigned short*)ws;    ws += (size_t)MM * 2 * DD * 2;   // 8MB
  unsigned short* vtb = (unsigned short*)ws;    ws += (size_t)MM * DD * 2;       // 4MB
  unsigned short* ho = (unsigned short*)ws;     ws += (size_t)MM * DD * 2;       // 4MB
  unsigned short* hm = (unsigned short*)ws;     ws += (size_t)MM * 4 * DD * 2;   // 16MB
  unsigned short* wqkv = (unsigned short*)ws;   ws += (size_t)3 * DD * DD * 2;   // 6MB (reused per layer)
  unsigned short* wproj = (unsigned short*)ws;  ws += (size_t)DD * DD * 2;       // 2MB
  unsigned short* wfc = (unsigned short*)ws;    ws += (size_t)4 * DD * DD * 2;   // 8MB
  unsigned short* wmp = (unsigned short*)ws;    ws += (size_t)DD * 4 * DD * 2;   // 8MB
  unsigned short* loraP = (unsigned short*)ws;  ws += (size_t)NL * 16384 * 32 * 2;  // 12.6MB

  hipLaunchKernelGGL(embed_cvt_k, dim3(MM * DD / 256 + NL * 16384 * 32 / 256), dim3(256),
                     0, stream, ids, wte, wpe, h,
                     attnla, attnlb, projla, projlb, fcla, fclb, mpla, mplb, loraP);

  for (int l = 0; l < NL; ++l) {
    const float* ab = attnb + (size_t)l * 3 * DD;
    const float* pb = projb + (size_t)l * DD;
    const float* fb = fcb + (size_t)l * 4 * DD;
    const float* mb = mpb + (size_t)l * DD;

    hipLaunchKernelGGL(fold_ln_k, dim3(1536 + MM), dim3(256), 0, stream,
                       attnw + (size_t)l * 3 * DD * DD, projw + (size_t)l * DD * DD,
                       fcw + (size_t)l * 4 * DD * DD, mpw + (size_t)l * DD * 4 * DD,
                       loraP + (size_t)l * 16384 * 32, wqkv, wproj, wfc, wmp,
                       h, ln1w + (size_t)l * DD, ln1b + (size_t)l * DD, x);

    hipLaunchKernelGGL((gemm_t<128, 64, 128, 3>), dim3(3 * DD / 64, MM / 128), dim3(256), 0,
                       stream, x, wqkv, ab, (const float*)nullptr, (float*)nullptr,
                       qkb, vtb, MM, 3 * DD, DD);
    hipLaunchKernelGGL(attn4_k, dim3(TT / 64, NB * NH), dim3(256), 0, stream, qkb, vtb, ho);
    hipLaunchKernelGGL((gemm_t<64, 64, 256, 1>), dim3(DD / 64, MM / 64), dim3(256), 0,
                       stream, ho, wproj, pb, h, h, (unsigned short*)nullptr,
                       (unsigned short*)nullptr, MM, DD, DD);
    hipLaunchKernelGGL(ln_bf_k, dim3(MM), dim3(256), 0, stream, h,
                       ln2w + (size_t)l * DD, ln2b + (size_t)l * DD, x);
    hipLaunchKernelGGL((gemm_t<128, 128, 128, 2>), dim3(4 * DD / 128, MM / 128), dim3(256), 0,
                       stream, x, wfc, fb, (const float*)nullptr, (float*)nullptr, hm,
                       (unsigned short*)nullptr, MM, 4 * DD, DD);
    hipLaunchKernelGGL((gemm_t<64, 64, 256, 1>), dim3(DD / 64, MM / 64), dim3(256), 0,
                       stream, hm, wmp, mb, h, h, (unsigned short*)nullptr,
                       (unsigned short*)nullptr, MM, DD, 4 * DD);
  }

  hipLaunchKernelGGL(ln_f_k, dim3(MM), dim3(256), 0, stream, h, lnfw, lnfb, (float*)d_out);
}

// Round 17
// 1686.320 us; speedup vs baseline: 1.0621x; 1.0221x over previous
//
#include <hip/hip_runtime.h>
#include <math.h>

#define TT 1024
#define DD 1024
#define NH 16
#define NB 2
#define NL 12
#define RR 32
#define MM (NB * TT)  // 2048

typedef __attribute__((ext_vector_type(8))) short bf16x8;
typedef __attribute__((ext_vector_type(4))) float f32x4;

__device__ __forceinline__ unsigned short f2bf(float f) {
  unsigned int u = __float_as_uint(f);
  u = (u + 0x7FFFu + ((u >> 16) & 1u)) >> 16;
  return (unsigned short)u;
}
__device__ __forceinline__ float bf2f(unsigned short u) {
  return __uint_as_float((unsigned int)u << 16);
}
// fast GELU (tanh form via exp2); |err| vs exact erf-GELU < ~1e-3, below bf16 rounding
__device__ __forceinline__ float gelu_fast(float v) {
  const float z = 0.7978845608f * (v + 0.044715f * v * v * v);
  const float e = exp2f(fminf(2.885390082f * z, 80.f));  // e^{2z}
  return v * e / (e + 1.f);
}

typedef __attribute__((address_space(1))) void gvoid;
typedef __attribute__((address_space(3))) void lvoid;
__device__ __forceinline__ void gload_lds16(const void* g, void* l) {
  __builtin_amdgcn_global_load_lds((gvoid*)g, (lvoid*)l, 16, 0, 0);
}

// ---------------------------------------------------------------- embed + LoRA cvt (merged, independent)
__global__ __launch_bounds__(256) void embed_cvt_k(
    const int* __restrict__ ids, const float* __restrict__ wte,
    const float* __restrict__ wpe, float* __restrict__ h,
    const float* __restrict__ ala, const float* __restrict__ alb,
    const float* __restrict__ pla, const float* __restrict__ plb,
    const float* __restrict__ fla, const float* __restrict__ flb,
    const float* __restrict__ mla, const float* __restrict__ mlb,
    unsigned short* __restrict__ out) {
  if (blockIdx.x < MM * DD / 256) {
    const int i = blockIdx.x * 256 + threadIdx.x;
    const int row = i >> 10;
    const int d = i & 1023;
    const int t = row & (TT - 1);
    const int id = ids[row];
    h[i] = wte[(size_t)id * DD + d] + wpe[(size_t)t * DD + d];
    return;
  }
  const int g = (blockIdx.x - MM * DD / 256) * 256 + threadIdx.x;  // over NL*16384*32
  const int layer = g >> 19;
  const int rem = g & 524287;
  const int row = rem >> 5;
  const int r = rem & 31;
  float v;
  if (row < 1024)       v = ala[(size_t)layer * 32 * 1024 + r * 1024 + row];
  else if (row < 4096)  v = alb[(size_t)layer * 3072 * 32 + (row - 1024) * 32 + r];
  else if (row < 5120)  v = pla[(size_t)layer * 32 * 1024 + r * 1024 + (row - 4096)];
  else if (row < 6144)  v = plb[(size_t)layer * 1024 * 32 + (row - 5120) * 32 + r];
  else if (row < 7168)  v = fla[(size_t)layer * 32 * 1024 + r * 1024 + (row - 6144)];
  else if (row < 11264) v = flb[(size_t)layer * 4096 * 32 + (row - 7168) * 32 + r];
  else if (row < 15360) v = mla[(size_t)layer * 32 * 4096 + r * 4096 + (row - 11264)];
  else                  v = mlb[(size_t)layer * 1024 * 32 + (row - 15360) * 32 + r];
  out[g] = f2bf(v);
}

// ---------------------------------------------------------------- layernorm (fp32 in, bf16 out)
__global__ __launch_bounds__(256) void ln_bf_k(const float* __restrict__ x,
                                               const float* __restrict__ w,
                                               const float* __restrict__ b,
                                               unsigned short* __restrict__ out) {
  const int row = blockIdx.x;
  const float* xr = x + (size_t)row * DD;
  const float4 v = *(const float4*)(xr + threadIdx.x * 4);
  float s = v.x + v.y + v.z + v.w;
  float ss = v.x * v.x + v.y * v.y + v.z * v.z + v.w * v.w;
#pragma unroll
  for (int off = 32; off > 0; off >>= 1) {
    s += __shfl_down(s, off);
    ss += __shfl_down(ss, off);
  }
  __shared__ float rs[4], rss[4];
  const int wid = threadIdx.x >> 6;
  if ((threadIdx.x & 63) == 0) { rs[wid] = s; rss[wid] = ss; }
  __syncthreads();
  s = rs[0] + rs[1] + rs[2] + rs[3];
  ss = rss[0] + rss[1] + rss[2] + rss[3];
  const float mean = s * (1.f / DD);
  const float var = ss * (1.f / DD) - mean * mean;
  const float rstd = rsqrtf(var + 1e-5f);
  const float4 wv = *(const float4*)(w + threadIdx.x * 4);
  const float4 bv = *(const float4*)(b + threadIdx.x * 4);
  ushort4 o;
  o.x = f2bf((v.x - mean) * rstd * wv.x + bv.x);
  o.y = f2bf((v.y - mean) * rstd * wv.y + bv.y);
  o.z = f2bf((v.z - mean) * rstd * wv.z + bv.z);
  o.w = f2bf((v.w - mean) * rstd * wv.w + bv.w);
  *(ushort4*)(out + (size_t)row * DD + threadIdx.x * 4) = o;
}

// final layernorm fp32 out
__global__ __launch_bounds__(256) void ln_f_k(const float* __restrict__ x,
                                              const float* __restrict__ w,
                                              const float* __restrict__ b,
                                              float* __restrict__ out) {
  const int row = blockIdx.x;
  const float* xr = x + (size_t)row * DD;
  const float4 v = *(const float4*)(xr + threadIdx.x * 4);
  float s = v.x + v.y + v.z + v.w;
  float ss = v.x * v.x + v.y * v.y + v.z * v.z + v.w * v.w;
#pragma unroll
  for (int off = 32; off > 0; off >>= 1) {
    s += __shfl_down(s, off);
    ss += __shfl_down(ss, off);
  }
  __shared__ float rs[4], rss[4];
  const int wid = threadIdx.x >> 6;
  if ((threadIdx.x & 63) == 0) { rs[wid] = s; rss[wid] = ss; }
  __syncthreads();
  s = rs[0] + rs[1] + rs[2] + rs[3];
  ss = rss[0] + rss[1] + rss[2] + rss[3];
  const float mean = s * (1.f / DD);
  const float var = ss * (1.f / DD) - mean * mean;
  const float rstd = rsqrtf(var + 1e-5f);
  const float4 wv = *(const float4*)(w + threadIdx.x * 4);
  const float4 bv = *(const float4*)(b + threadIdx.x * 4);
  float4 o;
  o.x = (v.x - mean) * rstd * wv.x + bv.x;
  o.y = (v.y - mean) * rstd * wv.y + bv.y;
  o.z = (v.z - mean) * rstd * wv.z + bv.z;
  o.w = (v.w - mean) * rstd * wv.w + bv.w;
  *(float4*)(out + (size_t)row * DD + threadIdx.x * 4) = o;
}

// ---------------------------------------------------------------- merged: LoRA fold (per-layer JIT) + LN1
__global__ __launch_bounds__(256) void fold_ln_k(
    const float* __restrict__ aw, const float* __restrict__ pw,
    const float* __restrict__ fw, const float* __restrict__ mw,
    const unsigned short* __restrict__ Lb,
    unsigned short* __restrict__ oq, unsigned short* __restrict__ op_,
    unsigned short* __restrict__ of, unsigned short* __restrict__ om,
    const float* __restrict__ hln, const float* __restrict__ lnw,
    const float* __restrict__ lnb, unsigned short* __restrict__ xout) {
  __shared__ unsigned short dl[64 * 128];  // 16KB (fold); LN reuses first 32B
  const int tid = threadIdx.x;
  if (blockIdx.x >= 1536) {
    const int row = blockIdx.x - 1536;
    const float* xr = hln + (size_t)row * DD;
    const float4 v = *(const float4*)(xr + tid * 4);
    float s = v.x + v.y + v.z + v.w;
    float ss = v.x * v.x + v.y * v.y + v.z * v.z + v.w * v.w;
#pragma unroll
    for (int off = 32; off > 0; off >>= 1) {
      s += __shfl_down(s, off);
      ss += __shfl_down(ss, off);
    }
    float* red = (float*)dl;
    const int wid = tid >> 6;
    if ((tid & 63) == 0) { red[wid] = s; red[4 + wid] = ss; }
    __syncthreads();
    s = red[0] + red[1] + red[2] + red[3];
    ss = red[4] + red[5] + red[6] + red[7];
    const float mean = s * (1.f / DD);
    const float var = ss * (1.f / DD) - mean * mean;
    const float rstd = rsqrtf(var + 1e-5f);
    const float4 wv = *(const float4*)(lnw + tid * 4);
    const float4 bv = *(const float4*)(lnb + tid * 4);
    ushort4 o;
    o.x = f2bf((v.x - mean) * rstd * wv.x + bv.x);
    o.y = f2bf((v.y - mean) * rstd * wv.y + bv.y);
    o.z = f2bf((v.z - mean) * rstd * wv.z + bv.z);
    o.w = f2bf((v.w - mean) * rstd * wv.w + bv.w);
    *(ushort4*)(xout + (size_t)row * DD + tid * 4) = o;
    return;
  }
  const int lid = blockIdx.x;  // 0..1535
  const float* W;
  unsigned short* out;
  const unsigned short *Bl, *Al;
  int K, n0, kblk;
  if (lid < 384) {
    W = aw; out = oq; Bl = Lb + 1024 * 32; Al = Lb;
    K = DD; n0 = (lid >> 3) * 64; kblk = (lid & 7) * 128;
  } else if (lid < 512) {
    const int t = lid - 384;
    W = pw; out = op_; Bl = Lb + 5120 * 32; Al = Lb + 4096 * 32;
    K = DD; n0 = (t >> 3) * 64; kblk = (t & 7) * 128;
  } else if (lid < 1024) {
    const int t = lid - 512;
    W = fw; out = of; Bl = Lb + 7168 * 32; Al = Lb + 6144 * 32;
    K = DD; n0 = (t >> 3) * 64; kblk = (t & 7) * 128;
  } else {
    const int t = lid - 1024;
    W = mw; out = om; Bl = Lb + 15360 * 32; Al = Lb + 11264 * 32;
    K = 4 * DD; n0 = (t >> 5) * 64; kblk = (t & 31) * 128;
  }
  const int w = tid >> 6, l = tid & 63;
  const int lr16 = l & 15, lg = l >> 4;
  const int nloc = w * 16 + lr16;
  const bf16x8 bfrag = *(const bf16x8*)(Bl + (size_t)(n0 + nloc) * 32 + lg * 8);
#pragma unroll
  for (int kc = 0; kc < 8; ++kc) {
    const bf16x8 afr = *(const bf16x8*)(Al + (size_t)(kblk + kc * 16 + lr16) * 32 + lg * 8);
    f32x4 acc = {};
    acc = __builtin_amdgcn_mfma_f32_16x16x32_bf16(afr, bfrag, acc, 0, 0, 0);
    ushort4 dv;
    dv.x = f2bf(2.f * acc[0]); dv.y = f2bf(2.f * acc[1]);
    dv.z = f2bf(2.f * acc[2]); dv.w = f2bf(2.f * acc[3]);
    const unsigned int byte = ((unsigned)(nloc * 256 + kc * 32 + lg * 8)) ^
                              (((unsigned)nloc & 3u) << 5);
    *(ushort4*)((char*)dl + byte) = dv;
  }
  __syncthreads();
  float4 wv[8];
#pragma unroll
  for (int it = 0; it < 8; ++it) {
    const int flat = it * 1024 + tid * 4;
    const int row = flat >> 7;
    const int k = flat & 127;
    wv[it] = *(const float4*)(W + (size_t)(n0 + row) * K + kblk + k);
  }
  asm volatile("s_waitcnt vmcnt(0)" ::: "memory");
#pragma unroll
  for (int it = 0; it < 8; ++it) {
    const int flat = it * 1024 + tid * 4;
    const int row = flat >> 7;
    const int k = flat & 127;
    const unsigned int byte = ((unsigned)(row * 256 + k * 2)) ^
                              (((unsigned)row & 3u) << 5);
    const ushort4 dv = *(const ushort4*)((const char*)dl + byte);
    ushort4 o;
    o.x = f2bf(wv[it].x + bf2f(dv.x));
    o.y = f2bf(wv[it].y + bf2f(dv.y));
    o.z = f2bf(wv[it].z + bf2f(dv.z));
    o.w = f2bf(wv[it].w + bf2f(dv.w));
    *(ushort4*)(out + (size_t)(n0 + row) * K + kblk + k) = o;
  }
}

// ---------------------------------------------------------------- unified bf16 MFMA GEMM
template <int BMt, int BNt, int BKt, int MODE>
__global__ __launch_bounds__(256) void gemm_t(const unsigned short* __restrict__ A,
                                              const unsigned short* __restrict__ Wt,
                                              const float* __restrict__ bias,
                                              const float* __restrict__ res,
                                              float* __restrict__ Cf,
                                              unsigned short* __restrict__ Cb,
                                              unsigned short* __restrict__ vt,
                                              int M, int N, int K) {
  constexpr int MI2 = BMt / 32, NJ2 = BNt / 32;
  constexpr int SB = BKt * 2;
  constexpr int SL = BKt / 8;
  constexpr int RC = 1024 / SB;
  constexpr int CAw = BMt / RC / 4;
  constexpr int CBw = BNt / RC / 4;
  __shared__ unsigned short As[BMt * BKt];
  __shared__ unsigned short Bs[BNt * BKt];
  const int tid = threadIdx.x;
  const int w = tid >> 6, l = tid & 63;
  const int gx = gridDim.x;
  const int bid = blockIdx.y * gx + blockIdx.x;
  const int cpx = (gx * gridDim.y) >> 3;
  const int logical = (bid & 7) * cpx + (bid >> 3);
  const int bm = (logical / gx) * BMt, bn = (logical % gx) * BNt;
  const int wr = w >> 1, wc = w & 1;
  const int lr16 = l & 15, lg = l >> 4, l7 = l & 7;
  const int rin = l / SL;
  const int slot = l % SL;
  f32x4 acc[MI2][NJ2] = {};
  for (int k0 = 0; k0 < K; k0 += BKt) {
    __syncthreads();
#pragma unroll
    for (int i = 0; i < CAw; ++i) {
      const int ch = w * CAw + i;
      const int row = ch * RC + rin;
      gload_lds16(A + (size_t)(bm + row) * K + k0 + ((slot ^ (row & 7)) * 8),
                  (char*)As + ch * 1024);
    }
#pragma unroll
    for (int i = 0; i < CBw; ++i) {
      const int ch = w * CBw + i;
      const int row = ch * RC + rin;
      gload_lds16(Wt + (size_t)(bn + row) * K + k0 + ((slot ^ (row & 7)) * 8),
                  (char*)Bs + ch * 1024);
    }
    __syncthreads();
#pragma unroll
    for (int kk = 0; kk < BKt / 32; ++kk) {
      bf16x8 af[MI2], bfr[NJ2];
      const int q = (kk * 4 + lg) ^ l7;
#pragma unroll
      for (int mi = 0; mi < MI2; ++mi)
        af[mi] = *(const bf16x8*)((const char*)As +
            (wr * (BMt / 2) + mi * 16 + lr16) * SB + q * 16);
#pragma unroll
      for (int nj = 0; nj < NJ2; ++nj)
        bfr[nj] = *(const bf16x8*)((const char*)Bs +
            (wc * (BNt / 2) + nj * 16 + lr16) * SB + q * 16);
#pragma unroll
      for (int mi = 0; mi < MI2; ++mi)
#pragma unroll
        for (int nj = 0; nj < NJ2; ++nj)
          acc[mi][nj] = __builtin_amdgcn_mfma_f32_16x16x32_bf16(
              af[mi], bfr[nj], acc[mi][nj], 0, 0, 0);
    }
  }
  const int cr = lg * 4;
  const int cc = lr16;
#pragma unroll
  for (int mi = 0; mi < MI2; ++mi) {
    const int gr0 = bm + wr * (BMt / 2) + mi * 16 + cr;
#pragma unroll
    for (int nj = 0; nj < NJ2; ++nj) {
      const int gc = bn + wc * (BNt / 2) + nj * 16 + cc;
      const float bv = bias[gc];
      if (MODE == 3) {
        if (gc < 2048) {
#pragma unroll
          for (int r = 0; r < 4; ++r)
            Cb[(size_t)(gr0 + r) * 2048 + gc] = f2bf(acc[mi][nj][r] + bv);
        } else {
          const int hv = gc - 2048;
          const int b_ = gr0 >> 10, t0 = gr0 & 1023;
          ushort4 u;
          u.x = f2bf(acc[mi][nj][0] + bv); u.y = f2bf(acc[mi][nj][1] + bv);
          u.z = f2bf(acc[mi][nj][2] + bv); u.w = f2bf(acc[mi][nj][3] + bv);
          *(ushort4*)(vt + ((size_t)(b_ * 1024 + hv)) * 1024 + t0) = u;
        }
      } else if (MODE == 1) {
#pragma unroll
        for (int r = 0; r < 4; ++r) {
          const size_t idx = (size_t)(gr0 + r) * N + gc;
          Cf[idx] = acc[mi][nj][r] + bv + res[idx];
        }
      } else {  // MODE 2: fast GELU -> bf16
#pragma unroll
        for (int r = 0; r < 4; ++r) {
          const float v = acc[mi][nj][r] + bv;
          Cb[(size_t)(gr0 + r) * N + gc] = f2bf(gelu_fast(v));
        }
      }
    }
  }
}

// ---------------------------------------------------------------- MFMA flash attention, KVBLK=128
// XCD-clustered: all 16 qt-tiles of a bh land on one XCD (K/V fetched once per XCD L2).
#define SM_SCALE_LOG2E 0.18033688011112042f  // log2(e)/8
__global__ __launch_bounds__(256) void attn4_k(const unsigned short* __restrict__ qk,
                                               const unsigned short* __restrict__ vt,
                                               unsigned short* __restrict__ out) {
  const int i = blockIdx.y * 16 + blockIdx.x;      // flat id, 512 blocks
  const int bh = (i & 7) + ((i >> 7) << 3);        // XCD (i&7) handles 4 bh values
  const int qt = 15 - ((i >> 3) & 15);             // heavy tiles first within XCD
  const int b = bh >> 4, hh = bh & 15;
  const int tid = threadIdx.x;
  const int w = tid >> 6, l = tid & 63;
  const int lg = l >> 4;
  const int lr = l & 15;

  __shared__ unsigned short Kt[2][128 * 64];
  __shared__ unsigned short Vb[2][64 * 128];
  __shared__ unsigned short Pb[4][16 * 128];

  bf16x8 qf[2];
  {
    const unsigned short* qp =
        qk + ((size_t)(b * TT + qt * 64 + w * 16 + lr)) * 2048 + hh * 64 + lg * 8;
    qf[0] = *(const bf16x8*)(qp);
    qf[1] = *(const bf16x8*)(qp + 32);
  }
  f32x4 oacc[4] = {};
  float mrow[4] = {-1e30f, -1e30f, -1e30f, -1e30f};
  float lrow[4] = {0.f, 0.f, 0.f, 0.f};

  auto stage = [&](int buf, int kt2) {
#pragma unroll
    for (int i2 = 0; i2 < 4; ++i2) {
      const int ch = w * 4 + i2;
      const int row = ch * 8 + (l >> 3);
      const int sc = ((l & 7) ^ (l >> 3)) * 8;
      const unsigned short* ks =
          qk + ((size_t)(b * TT + kt2 * 128 + row)) * 2048 + 1024 + hh * 64 + sc;
      gload_lds16(ks, (char*)&Kt[buf][0] + ch * 1024);
    }
#pragma unroll
    for (int i2 = 0; i2 < 4; ++i2) {
      const int ch = w * 4 + i2;
      const int row = ch * 4 + (l >> 4);
      const int sc = ((l & 15) ^ (row & 15)) * 8;
      const unsigned short* vs =
          vt + ((size_t)(bh * 64 + row)) * 1024 + kt2 * 128 + sc;
      gload_lds16(vs, (char*)&Vb[buf][0] + ch * 1024);
    }
  };

  const int nkt = (qt >> 1) + 1;
  stage(0, 0);
  int cur = 0;
  unsigned short* Pw = &Pb[w][0];
  const int qlocal = w * 16 + lg * 4;

  for (int kt2 = 0; kt2 < nkt; ++kt2) {
    __syncthreads();
    if (kt2 + 1 < nkt) stage(cur ^ 1, kt2 + 1);
    const unsigned short* Kb_ = &Kt[cur][0];
    const unsigned short* Vb_ = &Vb[cur][0];
    const bool last = (kt2 == nkt - 1);

    f32x4 s[8];
    __builtin_amdgcn_s_setprio(1);
#pragma unroll
    for (int j = 0; j < 8; ++j) {
      f32x4 sj = {};
#pragma unroll
      for (int ks = 0; ks < 2; ++ks) {
        const bf16x8 kf = *(const bf16x8*)((const char*)Kb_ + (j * 16 + lr) * 128 +
                                           (((ks * 4 + lg) ^ (lr & 7)) * 16));
        sj = __builtin_amdgcn_mfma_f32_16x16x32_bf16(qf[ks], kf, sj, 0, 0, 0);
      }
      s[j] = sj;
    }
    __builtin_amdgcn_s_setprio(0);

#pragma unroll
    for (int j = 0; j < 8; ++j)
#pragma unroll
      for (int r = 0; r < 4; ++r) {
        float v = s[j][r] * SM_SCALE_LOG2E;
        if (last && (kt2 * 128 + j * 16 + lr > qt * 64 + qlocal + r)) v = -1e30f;
        s[j][r] = v;
      }
    float corr[4];
#pragma unroll
    for (int r = 0; r < 4; ++r) {
      float mx = s[0][r];
#pragma unroll
      for (int j = 1; j < 8; ++j) mx = fmaxf(mx, s[j][r]);
      mx = fmaxf(mx, __shfl_xor(mx, 1));
      mx = fmaxf(mx, __shfl_xor(mx, 2));
      mx = fmaxf(mx, __shfl_xor(mx, 4));
      mx = fmaxf(mx, __shfl_xor(mx, 8));
      const float mn = fmaxf(mrow[r], mx);
      corr[r] = exp2f(mrow[r] - mn);
      mrow[r] = mn;
      lrow[r] *= corr[r];
    }
#pragma unroll
    for (int dt = 0; dt < 4; ++dt) {
      oacc[dt][0] *= corr[0]; oacc[dt][1] *= corr[1];
      oacc[dt][2] *= corr[2]; oacc[dt][3] *= corr[3];
    }
#pragma unroll
    for (int j = 0; j < 8; ++j)
#pragma unroll
      for (int r = 0; r < 4; ++r) {
        const float p = exp2f(s[j][r] - mrow[r]);
        lrow[r] += p;
        const int q = lg * 4 + r;
        const int kv = j * 16 + lr;
        *(unsigned short*)((char*)Pw + q * 256 + ((kv * 2) ^ ((q & 15) << 4))) = f2bf(p);
      }
    asm volatile("s_waitcnt lgkmcnt(0)" ::: "memory");
    __builtin_amdgcn_sched_barrier(0);

    __builtin_amdgcn_s_setprio(1);
#pragma unroll
    for (int ks = 0; ks < 4; ++ks) {
      const bf16x8 pf = *(const bf16x8*)((const char*)Pw + lr * 256 +
                                         (((ks * 4 + lg) ^ (lr & 15)) * 16));
#pragma unroll
      for (int dt = 0; dt < 4; ++dt) {
        const bf16x8 vf = *(const bf16x8*)((const char*)Vb_ + (dt * 16 + lr) * 256 +
                                           (((ks * 4 + lg) ^ (lr & 15)) * 16));
        oacc[dt] = __builtin_amdgcn_mfma_f32_16x16x32_bf16(pf, vf, oacc[dt], 0, 0, 0);
      }
    }
    __builtin_amdgcn_s_setprio(0);
    cur ^= 1;
  }

#pragma unroll
  for (int r = 0; r < 4; ++r) {
    float lv = lrow[r];
    lv += __shfl_xor(lv, 1);
    lv += __shfl_xor(lv, 2);
    lv += __shfl_xor(lv, 4);
    lv += __shfl_xor(lv, 8);
    lrow[r] = 1.f / lv;
  }
  unsigned short* ob = out + ((size_t)(b * TT + qt * 64 + w * 16 + lg * 4)) * 1024 + hh * 64 + lr;
#pragma unroll
  for (int r = 0; r < 4; ++r)
#pragma unroll
    for (int dt = 0; dt < 4; ++dt)
      ob[(size_t)r * 1024 + dt * 16] = f2bf(oacc[dt][r] * lrow[r]);
}

// ---------------------------------------------------------------- host
extern "C" void kernel_launch(void* const* d_in, const int* in_sizes, int n_in,
                              void* d_out, int out_size, void* d_ws, size_t ws_size,
                              hipStream_t stream) {
  (void)in_sizes; (void)n_in; (void)out_size; (void)ws_size;
  const int* ids = (const int*)d_in[0];
  const float* wte = (const float*)d_in[1];
  const float* wpe = (const float*)d_in[2];
  const float* ln1w = (const float*)d_in[3];
  const float* ln1b = (const float*)d_in[4];
  const float* attnw = (const float*)d_in[5];
  const float* attnb = (const float*)d_in[6];
  const float* attnla = (const float*)d_in[7];
  const float* attnlb = (const float*)d_in[8];
  const float* projw = (const float*)d_in[9];
  const float* projb = (const float*)d_in[10];
  const float* projla = (const float*)d_in[11];
  const float* projlb = (const float*)d_in[12];
  const float* ln2w = (const float*)d_in[13];
  const float* ln2b = (const float*)d_in[14];
  const float* fcw = (const float*)d_in[15];
  const float* fcb = (const float*)d_in[16];
  const float* fcla = (const float*)d_in[17];
  const float* fclb = (const float*)d_in[18];
  const float* mpw = (const float*)d_in[19];
  const float* mpb = (const float*)d_in[20];
  const float* mpla = (const float*)d_in[21];
  const float* mplb = (const float*)d_in[22];
  const float* lnfw = (const float*)d_in[23];
  const float* lnfb = (const float*)d_in[24];

  char* ws = (char*)d_ws;
  float* h = (float*)ws;                        ws += (size_t)MM * DD * 4;       // 8MB
  unsigned short* x = (unsigned short*)ws;      ws += (size_t)MM * DD * 2;       // 4MB
  unsigned short* qkb = (unsigned short*)ws;    ws += (size_t)MM * 2 * DD * 2;   // 8MB
  unsigned short* vtb = (unsigned short*)ws;    ws += (size_t)MM * DD * 2;       // 4MB
  unsigned short* ho = (unsigned short*)ws;     ws += (size_t)MM * DD * 2;       // 4MB
  unsigned short* hm = (unsigned short*)ws;     ws += (size_t)MM * 4 * DD * 2;   // 16MB
  unsigned short* wqkv = (unsigned short*)ws;   ws += (size_t)3 * DD * DD * 2;   // 6MB (reused per layer)
  unsigned short* wproj = (unsigned short*)ws;  ws += (size_t)DD * DD * 2;       // 2MB
  unsigned short* wfc = (unsigned short*)ws;    ws += (size_t)4 * DD * DD * 2;   // 8MB
  unsigned short* wmp = (unsigned short*)ws;    ws += (size_t)DD * 4 * DD * 2;   // 8MB
  unsigned short* loraP = (unsigned short*)ws;  ws += (size_t)NL * 16384 * 32 * 2;  // 12.6MB

  hipLaunchKernelGGL(embed_cvt_k, dim3(MM * DD / 256 + NL * 16384 * 32 / 256), dim3(256),
                     0, stream, ids, wte, wpe, h,
                     attnla, attnlb, projla, projlb, fcla, fclb, mpla, mplb, loraP);

  for (int l = 0; l < NL; ++l) {
    const float* ab = attnb + (size_t)l * 3 * DD;
    const float* pb = projb + (size_t)l * DD;
    const float* fb = fcb + (size_t)l * 4 * DD;
    const float* mb = mpb + (size_t)l * DD;

    hipLaunchKernelGGL(fold_ln_k, dim3(1536 + MM), dim3(256), 0, stream,
                       attnw + (size_t)l * 3 * DD * DD, projw + (size_t)l * DD * DD,
                       fcw + (size_t)l * 4 * DD * DD, mpw + (size_t)l * DD * 4 * DD,
                       loraP + (size_t)l * 16384 * 32, wqkv, wproj, wfc, wmp,
                       h, ln1w + (size_t)l * DD, ln1b + (size_t)l * DD, x);

    hipLaunchKernelGGL((gemm_t<128, 64, 128, 3>), dim3(3 * DD / 64, MM / 128), dim3(256), 0,
                       stream, x, wqkv, ab, (const float*)nullptr, (float*)nullptr,
                       qkb, vtb, MM, 3 * DD, DD);
    hipLaunchKernelGGL(attn4_k, dim3(TT / 64, NB * NH), dim3(256), 0, stream, qkb, vtb, ho);
    hipLaunchKernelGGL((gemm_t<64, 64, 256, 1>), dim3(DD / 64, MM / 64), dim3(256), 0,
                       stream, ho, wproj, pb, h, h, (unsigned short*)nullptr,
                       (unsigned short*)nullptr, MM, DD, DD);
    hipLaunchKernelGGL(ln_bf_k, dim3(MM), dim3(256), 0, stream, h,
                       ln2w + (size_t)l * DD, ln2b + (size_t)l * DD, x);
    hipLaunchKernelGGL((gemm_t<128, 128, 128, 2>), dim3(4 * DD / 128, MM / 128), dim3(256), 0,
                       stream, x, wfc, fb, (const float*)nullptr, (float*)nullptr, hm,
                       (unsigned short*)nullptr, MM, 4 * DD, DD);
    hipLaunchKernelGGL((gemm_t<64, 64, 256, 1>), dim3(DD / 64, MM / 64), dim3(256), 0,
                       stream, hm, wmp, mb, h, h, (unsigned short*)nullptr,
                       (unsigned short*)nullptr, MM, DD, 4 * DD);
  }

  hipLaunchKernelGGL(ln_f_k, dim3(MM), dim3(256), 0, stream, h, lnfw, lnfb, (float*)d_out);
}

// Round 19
// 1672.352 us; speedup vs baseline: 1.0710x; 1.0084x over previous
//
#include <hip/hip_runtime.h>
#include <math.h>

#define TT 1024
#define DD 1024
#define NH 16
#define NB 2
#define NL 12
#define RR 32
#define MM (NB * TT)  // 2048

typedef __attribute__((ext_vector_type(8))) short bf16x8;
typedef __attribute__((ext_vector_type(4))) float f32x4;

__device__ __forceinline__ unsigned short f2bf(float f) {
  unsigned int u = __float_as_uint(f);
  u = (u + 0x7FFFu + ((u >> 16) & 1u)) >> 16;
  return (unsigned short)u;
}
__device__ __forceinline__ float bf2f(unsigned short u) {
  return __uint_as_float((unsigned int)u << 16);
}
// fast GELU (tanh form via exp2); |err| vs exact erf-GELU < ~1e-3, below bf16 rounding
__device__ __forceinline__ float gelu_fast(float v) {
  const float z = 0.7978845608f * (v + 0.044715f * v * v * v);
  const float e = exp2f(fminf(2.885390082f * z, 80.f));  // e^{2z}
  return v * e / (e + 1.f);
}

typedef __attribute__((address_space(1))) void gvoid;
typedef __attribute__((address_space(3))) void lvoid;
__device__ __forceinline__ void gload_lds16(const void* g, void* l) {
  __builtin_amdgcn_global_load_lds((gvoid*)g, (lvoid*)l, 16, 0, 0);
}

// ---------------------------------------------------------------- embed + LoRA cvt (merged, independent)
__global__ __launch_bounds__(256) void embed_cvt_k(
    const int* __restrict__ ids, const float* __restrict__ wte,
    const float* __restrict__ wpe, float* __restrict__ h,
    const float* __restrict__ ala, const float* __restrict__ alb,
    const float* __restrict__ pla, const float* __restrict__ plb,
    const float* __restrict__ fla, const float* __restrict__ flb,
    const float* __restrict__ mla, const float* __restrict__ mlb,
    unsigned short* __restrict__ out) {
  if (blockIdx.x < MM * DD / 256) {
    const int i = blockIdx.x * 256 + threadIdx.x;
    const int row = i >> 10;
    const int d = i & 1023;
    const int t = row & (TT - 1);
    const int id = ids[row];
    h[i] = wte[(size_t)id * DD + d] + wpe[(size_t)t * DD + d];
    return;
  }
  const int g = (blockIdx.x - MM * DD / 256) * 256 + threadIdx.x;  // over NL*16384*32
  const int layer = g >> 19;
  const int rem = g & 524287;
  const int row = rem >> 5;
  const int r = rem & 31;
  float v;
  if (row < 1024)       v = ala[(size_t)layer * 32 * 1024 + r * 1024 + row];
  else if (row < 4096)  v = alb[(size_t)layer * 3072 * 32 + (row - 1024) * 32 + r];
  else if (row < 5120)  v = pla[(size_t)layer * 32 * 1024 + r * 1024 + (row - 4096)];
  else if (row < 6144)  v = plb[(size_t)layer * 1024 * 32 + (row - 5120) * 32 + r];
  else if (row < 7168)  v = fla[(size_t)layer * 32 * 1024 + r * 1024 + (row - 6144)];
  else if (row < 11264) v = flb[(size_t)layer * 4096 * 32 + (row - 7168) * 32 + r];
  else if (row < 15360) v = mla[(size_t)layer * 32 * 4096 + r * 4096 + (row - 11264)];
  else                  v = mlb[(size_t)layer * 1024 * 32 + (row - 15360) * 32 + r];
  out[g] = f2bf(v);
}

// ---------------------------------------------------------------- layernorm (fp32 in, bf16 out)
__global__ __launch_bounds__(256) void ln_bf_k(const float* __restrict__ x,
                                               const float* __restrict__ w,
                                               const float* __restrict__ b,
                                               unsigned short* __restrict__ out) {
  const int row = blockIdx.x;
  const float* xr = x + (size_t)row * DD;
  const float4 v = *(const float4*)(xr + threadIdx.x * 4);
  float s = v.x + v.y + v.z + v.w;
  float ss = v.x * v.x + v.y * v.y + v.z * v.z + v.w * v.w;
#pragma unroll
  for (int off = 32; off > 0; off >>= 1) {
    s += __shfl_down(s, off);
    ss += __shfl_down(ss, off);
  }
  __shared__ float rs[4], rss[4];
  const int wid = threadIdx.x >> 6;
  if ((threadIdx.x & 63) == 0) { rs[wid] = s; rss[wid] = ss; }
  __syncthreads();
  s = rs[0] + rs[1] + rs[2] + rs[3];
  ss = rss[0] + rss[1] + rss[2] + rss[3];
  const float mean = s * (1.f / DD);
  const float var = ss * (1.f / DD) - mean * mean;
  const float rstd = rsqrtf(var + 1e-5f);
  const float4 wv = *(const float4*)(w + threadIdx.x * 4);
  const float4 bv = *(const float4*)(b + threadIdx.x * 4);
  ushort4 o;
  o.x = f2bf((v.x - mean) * rstd * wv.x + bv.x);
  o.y = f2bf((v.y - mean) * rstd * wv.y + bv.y);
  o.z = f2bf((v.z - mean) * rstd * wv.z + bv.z);
  o.w = f2bf((v.w - mean) * rstd * wv.w + bv.w);
  *(ushort4*)(out + (size_t)row * DD + threadIdx.x * 4) = o;
}

// final layernorm fp32 out
__global__ __launch_bounds__(256) void ln_f_k(const float* __restrict__ x,
                                              const float* __restrict__ w,
                                              const float* __restrict__ b,
                                              float* __restrict__ out) {
  const int row = blockIdx.x;
  const float* xr = x + (size_t)row * DD;
  const float4 v = *(const float4*)(xr + threadIdx.x * 4);
  float s = v.x + v.y + v.z + v.w;
  float ss = v.x * v.x + v.y * v.y + v.z * v.z + v.w * v.w;
#pragma unroll
  for (int off = 32; off > 0; off >>= 1) {
    s += __shfl_down(s, off);
    ss += __shfl_down(ss, off);
  }
  __shared__ float rs[4], rss[4];
  const int wid = threadIdx.x >> 6;
  if ((threadIdx.x & 63) == 0) { rs[wid] = s; rss[wid] = ss; }
  __syncthreads();
  s = rs[0] + rs[1] + rs[2] + rs[3];
  ss = rss[0] + rss[1] + rss[2] + rss[3];
  const float mean = s * (1.f / DD);
  const float var = ss * (1.f / DD) - mean * mean;
  const float rstd = rsqrtf(var + 1e-5f);
  const float4 wv = *(const float4*)(w + threadIdx.x * 4);
  const float4 bv = *(const float4*)(b + threadIdx.x * 4);
  float4 o;
  o.x = (v.x - mean) * rstd * wv.x + bv.x;
  o.y = (v.y - mean) * rstd * wv.y + bv.y;
  o.z = (v.z - mean) * rstd * wv.z + bv.z;
  o.w = (v.w - mean) * rstd * wv.w + bv.w;
  *(float4*)(out + (size_t)row * DD + threadIdx.x * 4) = o;
}

// ---------------------------------------------------------------- merged: LoRA fold (per-layer JIT) + LN1
__global__ __launch_bounds__(256) void fold_ln_k(
    const float* __restrict__ aw, const float* __restrict__ pw,
    const float* __restrict__ fw, const float* __restrict__ mw,
    const unsigned short* __restrict__ Lb,
    unsigned short* __restrict__ oq, unsigned short* __restrict__ op_,
    unsigned short* __restrict__ of, unsigned short* __restrict__ om,
    const float* __restrict__ hln, const float* __restrict__ lnw,
    const float* __restrict__ lnb, unsigned short* __restrict__ xout) {
  __shared__ unsigned short dl[64 * 128];  // 16KB (fold); LN reuses first 32B
  const int tid = threadIdx.x;
  if (blockIdx.x >= 1536) {
    const int row = blockIdx.x - 1536;
    const float* xr = hln + (size_t)row * DD;
    const float4 v = *(const float4*)(xr + tid * 4);
    float s = v.x + v.y + v.z + v.w;
    float ss = v.x * v.x + v.y * v.y + v.z * v.z + v.w * v.w;
#pragma unroll
    for (int off = 32; off > 0; off >>= 1) {
      s += __shfl_down(s, off);
      ss += __shfl_down(ss, off);
    }
    float* red = (float*)dl;
    const int wid = tid >> 6;
    if ((tid & 63) == 0) { red[wid] = s; red[4 + wid] = ss; }
    __syncthreads();
    s = red[0] + red[1] + red[2] + red[3];
    ss = red[4] + red[5] + red[6] + red[7];
    const float mean = s * (1.f / DD);
    const float var = ss * (1.f / DD) - mean * mean;
    const float rstd = rsqrtf(var + 1e-5f);
    const float4 wv = *(const float4*)(lnw + tid * 4);
    const float4 bv = *(const float4*)(lnb + tid * 4);
    ushort4 o;
    o.x = f2bf((v.x - mean) * rstd * wv.x + bv.x);
    o.y = f2bf((v.y - mean) * rstd * wv.y + bv.y);
    o.z = f2bf((v.z - mean) * rstd * wv.z + bv.z);
    o.w = f2bf((v.w - mean) * rstd * wv.w + bv.w);
    *(ushort4*)(xout + (size_t)row * DD + tid * 4) = o;
    return;
  }
  const int lid = blockIdx.x;  // 0..1535
  const float* W;
  unsigned short* out;
  const unsigned short *Bl, *Al;
  int K, n0, kblk;
  if (lid < 384) {
    W = aw; out = oq; Bl = Lb + 1024 * 32; Al = Lb;
    K = DD; n0 = (lid >> 3) * 64; kblk = (lid & 7) * 128;
  } else if (lid < 512) {
    const int t = lid - 384;
    W = pw; out = op_; Bl = Lb + 5120 * 32; Al = Lb + 4096 * 32;
    K = DD; n0 = (t >> 3) * 64; kblk = (t & 7) * 128;
  } else if (lid < 1024) {
    const int t = lid - 512;
    W = fw; out = of; Bl = Lb + 7168 * 32; Al = Lb + 6144 * 32;
    K = DD; n0 = (t >> 3) * 64; kblk = (t & 7) * 128;
  } else {
    const int t = lid - 1024;
    W = mw; out = om; Bl = Lb + 15360 * 32; Al = Lb + 11264 * 32;
    K = 4 * DD; n0 = (t >> 5) * 64; kblk = (t & 31) * 128;
  }
  const int w = tid >> 6, l = tid & 63;
  const int lr16 = l & 15, lg = l >> 4;
  const int nloc = w * 16 + lr16;
  const bf16x8 bfrag = *(const bf16x8*)(Bl + (size_t)(n0 + nloc) * 32 + lg * 8);
#pragma unroll
  for (int kc = 0; kc < 8; ++kc) {
    const bf16x8 afr = *(const bf16x8*)(Al + (size_t)(kblk + kc * 16 + lr16) * 32 + lg * 8);
    f32x4 acc = {};
    acc = __builtin_amdgcn_mfma_f32_16x16x32_bf16(afr, bfrag, acc, 0, 0, 0);
    ushort4 dv;
    dv.x = f2bf(2.f * acc[0]); dv.y = f2bf(2.f * acc[1]);
    dv.z = f2bf(2.f * acc[2]); dv.w = f2bf(2.f * acc[3]);
    const unsigned int byte = ((unsigned)(nloc * 256 + kc * 32 + lg * 8)) ^
                              (((unsigned)nloc & 3u) << 5);
    *(ushort4*)((char*)dl + byte) = dv;
  }
  __syncthreads();
  float4 wv[8];
#pragma unroll
  for (int it = 0; it < 8; ++it) {
    const int flat = it * 1024 + tid * 4;
    const int row = flat >> 7;
    const int k = flat & 127;
    wv[it] = *(const float4*)(W + (size_t)(n0 + row) * K + kblk + k);
  }
  asm volatile("s_waitcnt vmcnt(0)" ::: "memory");
#pragma unroll
  for (int it = 0; it < 8; ++it) {
    const int flat = it * 1024 + tid * 4;
    const int row = flat >> 7;
    const int k = flat & 127;
    const unsigned int byte = ((unsigned)(row * 256 + k * 2)) ^
                              (((unsigned)row & 3u) << 5);
    const ushort4 dv = *(const ushort4*)((const char*)dl + byte);
    ushort4 o;
    o.x = f2bf(wv[it].x + bf2f(dv.x));
    o.y = f2bf(wv[it].y + bf2f(dv.y));
    o.z = f2bf(wv[it].z + bf2f(dv.z));
    o.w = f2bf(wv[it].w + bf2f(dv.w));
    *(ushort4*)(out + (size_t)(n0 + row) * K + kblk + k) = o;
  }
}

// ---------------------------------------------------------------- unified bf16 MFMA GEMM
// MODE 3 epilogue: LDS-repacked coalesced stores.
// Q/K: [row][col] stride 72 (col<64<72).  V: [col][row] stride 136 (row<128<136).
template <int BMt, int BNt, int BKt, int MODE>
__global__ __launch_bounds__(256) void gemm_t(const unsigned short* __restrict__ A,
                                              const unsigned short* __restrict__ Wt,
                                              const float* __restrict__ bias,
                                              const float* __restrict__ res,
                                              float* __restrict__ Cf,
                                              unsigned short* __restrict__ Cb,
                                              unsigned short* __restrict__ vt,
                                              int M, int N, int K) {
  constexpr int MI2 = BMt / 32, NJ2 = BNt / 32;
  constexpr int SB = BKt * 2;
  constexpr int SL = BKt / 8;
  constexpr int RC = 1024 / SB;
  constexpr int CAw = BMt / RC / 4;
  constexpr int CBw = BNt / RC / 4;
  __shared__ unsigned short As[BMt * BKt];
  __shared__ unsigned short Bs[BNt * BKt];
  const int tid = threadIdx.x;
  const int w = tid >> 6, l = tid & 63;
  const int gx = gridDim.x;
  const int bid = blockIdx.y * gx + blockIdx.x;
  const int cpx = (gx * gridDim.y) >> 3;
  const int logical = (bid & 7) * cpx + (bid >> 3);
  const int bm = (logical / gx) * BMt, bn = (logical % gx) * BNt;
  const int wr = w >> 1, wc = w & 1;
  const int lr16 = l & 15, lg = l >> 4, l7 = l & 7;
  const int rin = l / SL;
  const int slot = l % SL;
  f32x4 acc[MI2][NJ2] = {};
  for (int k0 = 0; k0 < K; k0 += BKt) {
    __syncthreads();
#pragma unroll
    for (int i = 0; i < CAw; ++i) {
      const int ch = w * CAw + i;
      const int row = ch * RC + rin;
      gload_lds16(A + (size_t)(bm + row) * K + k0 + ((slot ^ (row & 7)) * 8),
                  (char*)As + ch * 1024);
    }
#pragma unroll
    for (int i = 0; i < CBw; ++i) {
      const int ch = w * CBw + i;
      const int row = ch * RC + rin;
      gload_lds16(Wt + (size_t)(bn + row) * K + k0 + ((slot ^ (row & 7)) * 8),
                  (char*)Bs + ch * 1024);
    }
    __syncthreads();
#pragma unroll
    for (int kk = 0; kk < BKt / 32; ++kk) {
      bf16x8 af[MI2], bfr[NJ2];
      const int q = (kk * 4 + lg) ^ l7;
#pragma unroll
      for (int mi = 0; mi < MI2; ++mi)
        af[mi] = *(const bf16x8*)((const char*)As +
            (wr * (BMt / 2) + mi * 16 + lr16) * SB + q * 16);
#pragma unroll
      for (int nj = 0; nj < NJ2; ++nj)
        bfr[nj] = *(const bf16x8*)((const char*)Bs +
            (wc * (BNt / 2) + nj * 16 + lr16) * SB + q * 16);
#pragma unroll
      for (int mi = 0; mi < MI2; ++mi)
#pragma unroll
        for (int nj = 0; nj < NJ2; ++nj)
          acc[mi][nj] = __builtin_amdgcn_mfma_f32_16x16x32_bf16(
              af[mi], bfr[nj], acc[mi][nj], 0, 0, 0);
    }
  }
  const int cr = lg * 4;
  const int cc = lr16;
  if (MODE == 3) {
    // ---- coalesced epilogue via LDS repack (As free after loop; 32KB for BK=128)
    __syncthreads();
    const bool isV = (bn >= 2048);
    if (!isV) {
      // pack [row][col], stride 72 shorts (col < 64 < 72)
#pragma unroll
      for (int mi = 0; mi < MI2; ++mi)
#pragma unroll
        for (int nj = 0; nj < NJ2; ++nj) {
          const int col = wc * (BNt / 2) + nj * 16 + lr16;
          const float bv = bias[bn + col];
#pragma unroll
          for (int r = 0; r < 4; ++r) {
            const int row = wr * (BMt / 2) + mi * 16 + cr + r;
            As[row * 72 + col] = f2bf(acc[mi][nj][r] + bv);
          }
        }
      __syncthreads();
#pragma unroll
      for (int c4 = 0; c4 < 4; ++c4) {
        const int c = c4 * 256 + tid;           // 0..1023 over 128 rows x 8 chunks
        const int row = c >> 3;
        const int off = (c & 7) * 8;
        *(bf16x8*)(Cb + (size_t)(bm + row) * 2048 + bn + off) =
            *(const bf16x8*)(As + row * 72 + off);
      }
    } else {
      // pack transposed [col][rowpos], stride 136 shorts (rowpos < 128 < 136)
#pragma unroll
      for (int mi = 0; mi < MI2; ++mi)
#pragma unroll
        for (int nj = 0; nj < NJ2; ++nj) {
          const int col = wc * (BNt / 2) + nj * 16 + lr16;
          const float bv = bias[bn + col];
          ushort4 u;
          u.x = f2bf(acc[mi][nj][0] + bv);
          u.y = f2bf(acc[mi][nj][1] + bv);
          u.z = f2bf(acc[mi][nj][2] + bv);
          u.w = f2bf(acc[mi][nj][3] + bv);
          const int rowp = wr * (BMt / 2) + mi * 16 + cr;
          *(ushort4*)(As + col * 136 + rowp) = u;
        }
      __syncthreads();
      const int b_ = bm >> 10, t0 = bm & 1023;
#pragma unroll
      for (int c4 = 0; c4 < 4; ++c4) {
        const int c = c4 * 256 + tid;           // 0..1023 over 64 hv x 16 chunks
        const int hv = c >> 4;
        const int toff = (c & 15) * 8;
        *(bf16x8*)(vt + ((size_t)(b_ * 1024 + bn - 2048 + hv)) * 1024 + t0 + toff) =
            *(const bf16x8*)(As + hv * 136 + toff);
      }
    }
    return;
  }
#pragma unroll
  for (int mi = 0; mi < MI2; ++mi) {
    const int gr0 = bm + wr * (BMt / 2) + mi * 16 + cr;
#pragma unroll
    for (int nj = 0; nj < NJ2; ++nj) {
      const int gc = bn + wc * (BNt / 2) + nj * 16 + cc;
      const float bv = bias[gc];
      if (MODE == 1) {
#pragma unroll
        for (int r = 0; r < 4; ++r) {
          const size_t idx = (size_t)(gr0 + r) * N + gc;
          Cf[idx] = acc[mi][nj][r] + bv + res[idx];
        }
      } else {  // MODE 2: fast GELU -> bf16
#pragma unroll
        for (int r = 0; r < 4; ++r) {
          const float v = acc[mi][nj][r] + bv;
          Cb[(size_t)(gr0 + r) * N + gc] = f2bf(gelu_fast(v));
        }
      }
    }
  }
}

// ---------------------------------------------------------------- MFMA flash attention, KVBLK=128
// XCD-clustered: all 16 qt-tiles of a bh land on one XCD (K/V fetched once per XCD L2).
#define SM_SCALE_LOG2E 0.18033688011112042f  // log2(e)/8
__global__ __launch_bounds__(256) void attn4_k(const unsigned short* __restrict__ qk,
                                               const unsigned short* __restrict__ vt,
                                               unsigned short* __restrict__ out) {
  const int i = blockIdx.y * 16 + blockIdx.x;      // flat id, 512 blocks
  const int bh = (i & 7) + ((i >> 7) << 3);        // XCD (i&7) handles 4 bh values
  const int qt = 15 - ((i >> 3) & 15);             // heavy tiles first within XCD
  const int b = bh >> 4, hh = bh & 15;
  const int tid = threadIdx.x;
  const int w = tid >> 6, l = tid & 63;
  const int lg = l >> 4;
  const int lr = l & 15;

  __shared__ unsigned short Kt[2][128 * 64];
  __shared__ unsigned short Vb[2][64 * 128];
  __shared__ unsigned short Pb[4][16 * 128];

  bf16x8 qf[2];
  {
    const unsigned short* qp =
        qk + ((size_t)(b * TT + qt * 64 + w * 16 + lr)) * 2048 + hh * 64 + lg * 8;
    qf[0] = *(const bf16x8*)(qp);
    qf[1] = *(const bf16x8*)(qp + 32);
  }
  f32x4 oacc[4] = {};
  float mrow[4] = {-1e30f, -1e30f, -1e30f, -1e30f};
  float lrow[4] = {0.f, 0.f, 0.f, 0.f};

  auto stage = [&](int buf, int kt2) {
#pragma unroll
    for (int i2 = 0; i2 < 4; ++i2) {
      const int ch = w * 4 + i2;
      const int row = ch * 8 + (l >> 3);
      const int sc = ((l & 7) ^ (l >> 3)) * 8;
      const unsigned short* ks =
          qk + ((size_t)(b * TT + kt2 * 128 + row)) * 2048 + 1024 + hh * 64 + sc;
      gload_lds16(ks, (char*)&Kt[buf][0] + ch * 1024);
    }
#pragma unroll
    for (int i2 = 0; i2 < 4; ++i2) {
      const int ch = w * 4 + i2;
      const int row = ch * 4 + (l >> 4);
      const int sc = ((l & 15) ^ (row & 15)) * 8;
      const unsigned short* vs =
          vt + ((size_t)(bh * 64 + row)) * 1024 + kt2 * 128 + sc;
      gload_lds16(vs, (char*)&Vb[buf][0] + ch * 1024);
    }
  };

  const int nkt = (qt >> 1) + 1;
  stage(0, 0);
  int cur = 0;
  unsigned short* Pw = &Pb[w][0];
  const int qlocal = w * 16 + lg * 4;

  for (int kt2 = 0; kt2 < nkt; ++kt2) {
    __syncthreads();
    if (kt2 + 1 < nkt) stage(cur ^ 1, kt2 + 1);
    const unsigned short* Kb_ = &Kt[cur][0];
    const unsigned short* Vb_ = &Vb[cur][0];
    const bool last = (kt2 == nkt - 1);

    f32x4 s[8];
    __builtin_amdgcn_s_setprio(1);
#pragma unroll
    for (int j = 0; j < 8; ++j) {
      f32x4 sj = {};
#pragma unroll
      for (int ks = 0; ks < 2; ++ks) {
        const bf16x8 kf = *(const bf16x8*)((const char*)Kb_ + (j * 16 + lr) * 128 +
                                           (((ks * 4 + lg) ^ (lr & 7)) * 16));
        sj = __builtin_amdgcn_mfma_f32_16x16x32_bf16(qf[ks], kf, sj, 0, 0, 0);
      }
      s[j] = sj;
    }
    __builtin_amdgcn_s_setprio(0);

#pragma unroll
    for (int j = 0; j < 8; ++j)
#pragma unroll
      for (int r = 0; r < 4; ++r) {
        float v = s[j][r] * SM_SCALE_LOG2E;
        if (last && (kt2 * 128 + j * 16 + lr > qt * 64 + qlocal + r)) v = -1e30f;
        s[j][r] = v;
      }
    float corr[4];
#pragma unroll
    for (int r = 0; r < 4; ++r) {
      float mx = s[0][r];
#pragma unroll
      for (int j = 1; j < 8; ++j) mx = fmaxf(mx, s[j][r]);
      mx = fmaxf(mx, __shfl_xor(mx, 1));
      mx = fmaxf(mx, __shfl_xor(mx, 2));
      mx = fmaxf(mx, __shfl_xor(mx, 4));
      mx = fmaxf(mx, __shfl_xor(mx, 8));
      const float mn = fmaxf(mrow[r], mx);
      corr[r] = exp2f(mrow[r] - mn);
      mrow[r] = mn;
      lrow[r] *= corr[r];
    }
#pragma unroll
    for (int dt = 0; dt < 4; ++dt) {
      oacc[dt][0] *= corr[0]; oacc[dt][1] *= corr[1];
      oacc[dt][2] *= corr[2]; oacc[dt][3] *= corr[3];
    }
#pragma unroll
    for (int j = 0; j < 8; ++j)
#pragma unroll
      for (int r = 0; r < 4; ++r) {
        const float p = exp2f(s[j][r] - mrow[r]);
        lrow[r] += p;
        const int q = lg * 4 + r;
        const int kv = j * 16 + lr;
        *(unsigned short*)((char*)Pw + q * 256 + ((kv * 2) ^ ((q & 15) << 4))) = f2bf(p);
      }
    asm volatile("s_waitcnt lgkmcnt(0)" ::: "memory");
    __builtin_amdgcn_sched_barrier(0);

    __builtin_amdgcn_s_setprio(1);
#pragma unroll
    for (int ks = 0; ks < 4; ++ks) {
      const bf16x8 pf = *(const bf16x8*)((const char*)Pw + lr * 256 +
                                         (((ks * 4 + lg) ^ (lr & 15)) * 16));
#pragma unroll
      for (int dt = 0; dt < 4; ++dt) {
        const bf16x8 vf = *(const bf16x8*)((const char*)Vb_ + (dt * 16 + lr) * 256 +
                                           (((ks * 4 + lg) ^ (lr & 15)) * 16));
        oacc[dt] = __builtin_amdgcn_mfma_f32_16x16x32_bf16(pf, vf, oacc[dt], 0, 0, 0);
      }
    }
    __builtin_amdgcn_s_setprio(0);
    cur ^= 1;
  }

#pragma unroll
  for (int r = 0; r < 4; ++r) {
    float lv = lrow[r];
    lv += __shfl_xor(lv, 1);
    lv += __shfl_xor(lv, 2);
    lv += __shfl_xor(lv, 4);
    lv += __shfl_xor(lv, 8);
    lrow[r] = 1.f / lv;
  }
  unsigned short* ob = out + ((size_t)(b * TT + qt * 64 + w * 16 + lg * 4)) * 1024 + hh * 64 + lr;
#pragma unroll
  for (int r = 0; r < 4; ++r)
#pragma unroll
    for (int dt = 0; dt < 4; ++dt)
      ob[(size_t)r * 1024 + dt * 16] = f2bf(oacc[dt][r] * lrow[r]);
}

// ---------------------------------------------------------------- host
extern "C" void kernel_launch(void* const* d_in, const int* in_sizes, int n_in,
                              void* d_out, int out_size, void* d_ws, size_t ws_size,
                              hipStream_t stream) {
  (void)in_sizes; (void)n_in; (void)out_size; (void)ws_size;
  const int* ids = (const int*)d_in[0];
  const float* wte = (const float*)d_in[1];
  const float* wpe = (const float*)d_in[2];
  const float* ln1w = (const float*)d_in[3];
  const float* ln1b = (const float*)d_in[4];
  const float* attnw = (const float*)d_in[5];
  const float* attnb = (const float*)d_in[6];
  const float* attnla = (const float*)d_in[7];
  const float* attnlb = (const float*)d_in[8];
  const float* projw = (const float*)d_in[9];
  const float* projb = (const float*)d_in[10];
  const float* projla = (const float*)d_in[11];
  const float* projlb = (const float*)d_in[12];
  const float* ln2w = (const float*)d_in[13];
  const float* ln2b = (const float*)d_in[14];
  const float* fcw = (const float*)d_in[15];
  const float* fcb = (const float*)d_in[16];
  const float* fcla = (const float*)d_in[17];
  const float* fclb = (const float*)d_in[18];
  const float* mpw = (const float*)d_in[19];
  const float* mpb = (const float*)d_in[20];
  const float* mpla = (const float*)d_in[21];
  const float* mplb = (const float*)d_in[22];
  const float* lnfw = (const float*)d_in[23];
  const float* lnfb = (const float*)d_in[24];

  char* ws = (char*)d_ws;
  float* h = (float*)ws;                        ws += (size_t)MM * DD * 4;       // 8MB
  unsigned short* x = (unsigned short*)ws;      ws += (size_t)MM * DD * 2;       // 4MB
  unsigned short* qkb = (unsigned short*)ws;    ws += (size_t)MM * 2 * DD * 2;   // 8MB
  unsigned short* vtb = (unsigned short*)ws;    ws += (size_t)MM * DD * 2;       // 4MB
  unsigned short* ho = (unsigned short*)ws;     ws += (size_t)MM * DD * 2;       // 4MB
  unsigned short* hm = (unsigned short*)ws;     ws += (size_t)MM * 4 * DD * 2;   // 16MB
  unsigned short* wqkv = (unsigned short*)ws;   ws += (size_t)3 * DD * DD * 2;   // 6MB (reused per layer)
  unsigned short* wproj = (unsigned short*)ws;  ws += (size_t)DD * DD * 2;       // 2MB
  unsigned short* wfc = (unsigned short*)ws;    ws += (size_t)4 * DD * DD * 2;   // 8MB
  unsigned short* wmp = (unsigned short*)ws;    ws += (size_t)DD * 4 * DD * 2;   // 8MB
  unsigned short* loraP = (unsigned short*)ws;  ws += (size_t)NL * 16384 * 32 * 2;  // 12.6MB

  hipLaunchKernelGGL(embed_cvt_k, dim3(MM * DD / 256 + NL * 16384 * 32 / 256), dim3(256),
                     0, stream, ids, wte, wpe, h,
                     attnla, attnlb, projla, projlb, fcla, fclb, mpla, mplb, loraP);

  for (int l = 0; l < NL; ++l) {
    const float* ab = attnb + (size_t)l * 3 * DD;
    const float* pb = projb + (size_t)l * DD;
    const float* fb = fcb + (size_t)l * 4 * DD;
    const float* mb = mpb + (size_t)l * DD;

    hipLaunchKernelGGL(fold_ln_k, dim3(1536 + MM), dim3(256), 0, stream,
                       attnw + (size_t)l * 3 * DD * DD, projw + (size_t)l * DD * DD,
                       fcw + (size_t)l * 4 * DD * DD, mpw + (size_t)l * DD * 4 * DD,
                       loraP + (size_t)l * 16384 * 32, wqkv, wproj, wfc, wmp,
                       h, ln1w + (size_t)l * DD, ln1b + (size_t)l * DD, x);

    hipLaunchKernelGGL((gemm_t<128, 64, 128, 3>), dim3(3 * DD / 64, MM / 128), dim3(256), 0,
                       stream, x, wqkv, ab, (const float*)nullptr, (float*)nullptr,
                       qkb, vtb, MM, 3 * DD, DD);
    hipLaunchKernelGGL(attn4_k, dim3(TT / 64, NB * NH), dim3(256), 0, stream, qkb, vtb, ho);
    hipLaunchKernelGGL((gemm_t<64, 64, 256, 1>), dim3(DD / 64, MM / 64), dim3(256), 0,
                       stream, ho, wproj, pb, h, h, (unsigned short*)nullptr,
                       (unsigned short*)nullptr, MM, DD, DD);
    hipLaunchKernelGGL(ln_bf_k, dim3(MM), dim3(256), 0, stream, h,
                       ln2w + (size_t)l * DD, ln2b + (size_t)l * DD, x);
    hipLaunchKernelGGL((gemm_t<128, 128, 128, 2>), dim3(4 * DD / 128, MM / 128), dim3(256), 0,
                       stream, x, wfc, fb, (const float*)nullptr, (float*)nullptr, hm,
                       (unsigned short*)nullptr, MM, 4 * DD, DD);
    hipLaunchKernelGGL((gemm_t<64, 64, 256, 1>), dim3(DD / 64, MM / 64), dim3(256), 0,
                       stream, hm, wmp, mb, h, h, (unsigned short*)nullptr,
                       (unsigned short*)nullptr, MM, DD, 4 * DD);
  }

  hipLaunchKernelGGL(ln_f_k, dim3(MM), dim3(256), 0, stream, h, lnfw, lnfb, (float*)d_out);
}